// Round 15
// baseline (174.876 us; speedup 1.0000x reference)
//
#include <hip/hip_runtime.h>
#include <hip/hip_bf16.h>

typedef unsigned short u16;
typedef u16  u16x8 __attribute__((ext_vector_type(8)));
typedef u16  u16x4 __attribute__((ext_vector_type(4)));
typedef short bf16x8 __attribute__((ext_vector_type(8)));
typedef float f32x4 __attribute__((ext_vector_type(4)));

#define D_MODEL 1024
#define T_SEQ   2048
#define BATCH   4
#define NHEAD   16
#define DHEAD   64
#define MROWS   (BATCH*T_SEQ)   /* 8192 */
#define K2LOG2E 0.18033688011112042f   /* log2(e)/sqrt(DHEAD) */

#define MFMA(a,b,c) __builtin_amdgcn_mfma_f32_16x16x32_bf16(a,b,c,0,0,0)

__device__ __forceinline__ u16 f2bf(float f) {
  __hip_bfloat16 h = __float2bfloat16(f);
  u16 r; __builtin_memcpy(&r, &h, 2); return r;
}
// v_cvt_pk_bf16_f32: low16 = bf16(lo), high16 = bf16(hi), RNE
__device__ __forceinline__ unsigned cvtpk(float lo, float hi) {
  unsigned r;
  asm("v_cvt_pk_bf16_f32 %0, %1, %2" : "=v"(r) : "v"(lo), "v"(hi));
  return r;
}

// async global -> LDS, 16B per lane (dest = wave-uniform base + lane*16)
__device__ __forceinline__ void gload16(const void* g, void* l) {
  __builtin_amdgcn_global_load_lds(
      (const __attribute__((address_space(1))) void*)g,
      (__attribute__((address_space(3))) void*)l, 16, 0, 0);
}

// T1 XCD swizzle: HW assigns flat block f to XCD f%8; remap so the WORK id
// w = (f&7)*cpx + (f>>3) gives contiguous work chunks per XCD (bijective when
// nwg % 8 == 0; cpx = nwg/8). Work w runs on XCD w/cpx.
__device__ __forceinline__ int xcd_swz(int f, int cpx) {
  return (f & 7) * cpx + (f >> 3);
}

// ---------------- prep: x fp32 -> bf16 ----------------
__global__ void cvt_x_kernel(const float* __restrict__ x, u16* __restrict__ xb, int n8) {
  int i = blockIdx.x * blockDim.x + threadIdx.x;
  if (i >= n8) return;
  const f32x4* p = (const f32x4*)(x + (size_t)i * 8);
  f32x4 a = p[0], b = p[1];
  union { u16x8 v; unsigned u[4]; } o;
  o.u[0] = cvtpk(a[0], a[1]); o.u[1] = cvtpk(a[2], a[3]);
  o.u[2] = cvtpk(b[0], b[1]); o.u[3] = cvtpk(b[2], b[3]);
  *(u16x8*)(xb + (size_t)i * 8) = o.v;
}

// ---------------- prep: W [K][N] fp32 -> Wt [N][K] bf16 ----------------
__global__ void transpose_w_kernel(const float* __restrict__ w0, const float* __restrict__ w1,
                                   const float* __restrict__ w2, const float* __restrict__ w3,
                                   u16* __restrict__ o0, u16* __restrict__ o1,
                                   u16* __restrict__ o2, u16* __restrict__ o3) {
  const float* W; u16* O;
  if      (blockIdx.z == 0) { W = w0; O = o0; }
  else if (blockIdx.z == 1) { W = w1; O = o1; }
  else if (blockIdx.z == 2) { W = w2; O = o2; }
  else                      { W = w3; O = o3; }
  __shared__ float t[32][33];
  int tx = threadIdx.x, ty = threadIdx.y;
  int k0 = blockIdx.y * 32, n0 = blockIdx.x * 32;
#pragma unroll
  for (int j = 0; j < 4; j++)
    t[ty + 8 * j][tx] = W[(size_t)(k0 + ty + 8 * j) * D_MODEL + n0 + tx];
  __syncthreads();
#pragma unroll
  for (int j = 0; j < 4; j++)
    O[(size_t)(n0 + ty + 8 * j) * D_MODEL + k0 + tx] = f2bf(t[tx][ty + 8 * j]);
}

// ---------------- GEMM: C = (A[M,K] * Bt[N,K]^T + bias) * oscale ----------------
// R14 structure: double-buffered K-loop, stage(k+1) at iter top (gload16),
// ONE barrier per iter. BK=64, linear LDS [128][64], both-sides XOR swizzle.
// trans==0: out[m*N + n]; trans==1 (bf16): out[n*M + perm64(m)]  (V^T for attn)
template<int BF16OUT>
__device__ __forceinline__ void gemm_body(const u16* __restrict__ A, const u16* __restrict__ Bt,
                                          const float* __restrict__ bias, void* __restrict__ outp,
                                          int M, int N, int K, float oscale, int trans,
                                          int m0, int n0) {
  __shared__ u16 As[2][128 * 64];   // 32 KB
  __shared__ u16 Bs[2][128 * 64];   // 32 KB
  int tid = threadIdx.x;
  int lane = tid & 63, w = tid >> 6;
  int l15 = lane & 15, hi = lane >> 4;
  int wr = w >> 1, wc = w & 1;
  int srow = lane >> 3, su = lane & 7;
  f32x4 acc[4][4] = {};

  // loop-carried staging pointers (compile-time-indexed arrays -> registers)
  const u16* ap[4]; const u16* bp[4];
#pragma unroll
  for (int p = 0; p < 4; p++) {
    int row = (w * 4 + p) * 8 + srow;
    int cb  = su ^ (row & 7);
    ap[p] = A  + (size_t)(m0 + row) * K + cb * 8;
    bp[p] = Bt + (size_t)(n0 + row) * K + cb * 8;
  }

  // prologue: stage k-tile 0 -> buffer 0
#pragma unroll
  for (int p = 0; p < 4; p++) {
    gload16(ap[p], &As[0][(w * 4 + p) * 512]);
    gload16(bp[p], &Bs[0][(w * 4 + p) * 512]);
    ap[p] += 64; bp[p] += 64;
  }
  __syncthreads();

  const int NK = K / 64;
  for (int kk = 0; kk < NK; kk++) {
    int cur = kk & 1;
    // issue next k-tile's staging into the other buffer (read finished last iter)
    if (kk + 1 < NK) {
      int nxt = cur ^ 1;
#pragma unroll
      for (int p = 0; p < 4; p++) {
        gload16(ap[p], &As[nxt][(w * 4 + p) * 512]);
        gload16(bp[p], &Bs[nxt][(w * 4 + p) * 512]);
        ap[p] += 64; bp[p] += 64;
      }
    }
#pragma unroll
    for (int s = 0; s < 2; s++) {
      bf16x8 af[4], bfr[4];
#pragma unroll
      for (int i = 0; i < 4; i++) {
        int ra = wr * 64 + i * 16 + l15;
        af[i]  = *(const bf16x8*)&As[cur][ra * 64 + ((s * 4 + hi) ^ (ra & 7)) * 8];
        int rb = wc * 64 + i * 16 + l15;
        bfr[i] = *(const bf16x8*)&Bs[cur][rb * 64 + ((s * 4 + hi) ^ (rb & 7)) * 8];
      }
      __builtin_amdgcn_s_setprio(1);
#pragma unroll
      for (int i = 0; i < 4; i++)
#pragma unroll
        for (int j = 0; j < 4; j++)
          acc[i][j] = MFMA(af[i], bfr[j], acc[i][j]);
      __builtin_amdgcn_s_setprio(0);
    }
    __syncthreads();   // drains vmcnt: stage(kk+1) landed; reads(kk) done
  }

  // C/D layout: col = lane&15, row = (lane>>4)*4 + reg
  if (trans) {
#pragma unroll
    for (int j = 0; j < 4; j++) {
      int n = n0 + wc * 64 + j * 16 + l15;
      float bv = bias[n];
#pragma unroll
      for (int i = 0; i < 4; i++) {
        int mb = m0 + wr * 64 + i * 16 + hi * 4;
        int off = mb & 63;
        int colp = (off & 32) + (((off >> 2) & 3) << 3) + (((off >> 4) & 1) << 2);
        union { u16x4 v; unsigned u[2]; } t;
        t.u[0] = cvtpk((acc[i][j][0] + bv) * oscale, (acc[i][j][1] + bv) * oscale);
        t.u[1] = cvtpk((acc[i][j][2] + bv) * oscale, (acc[i][j][3] + bv) * oscale);
        *(u16x4*)((u16*)outp + (size_t)n * M + (mb - off) + colp) = t.v;
      }
    }
  } else {
#pragma unroll
    for (int j = 0; j < 4; j++) {
      int n = n0 + wc * 64 + j * 16 + l15;
      float bv = bias[n];
#pragma unroll
      for (int i = 0; i < 4; i++) {
        int mbase = m0 + wr * 64 + i * 16 + hi * 4;
#pragma unroll
        for (int r = 0; r < 4; r++) {
          float v = (acc[i][j][r] + bv) * oscale;
          if (BF16OUT) ((u16*)outp)[(size_t)(mbase + r) * N + n] = f2bf(v);
          else        ((float*)outp)[(size_t)(mbase + r) * N + n] = v;
        }
      }
    }
  }
}

// grid (8, 64, 3): flat f = (z*64+y)*8+x, nwg=1536, cpx=192
__global__ __launch_bounds__(256) void gemm_qkv_kernel(
    const u16* __restrict__ A,
    const u16* __restrict__ Btq, const u16* __restrict__ Btk, const u16* __restrict__ Btv,
    const float* __restrict__ bq, const float* __restrict__ bk, const float* __restrict__ bv,
    u16* __restrict__ oq, u16* __restrict__ ok, u16* __restrict__ ov) {
  int f = (blockIdx.z * 64 + blockIdx.y) * 8 + blockIdx.x;
  int wk = xcd_swz(f, 192);
  int bx = wk & 7, by = (wk >> 3) & 63, bz = wk >> 9;
  const u16* Bt; const float* bias; u16* o; float sc; int tr;
  if      (bz == 0) { Bt = Btq; bias = bq; o = oq; sc = K2LOG2E; tr = 0; }  // Q pre-scaled
  else if (bz == 1) { Bt = Btk; bias = bk; o = ok; sc = 1.0f; tr = 0; }
  else              { Bt = Btv; bias = bv; o = ov; sc = 1.0f; tr = 1; }     // V^T, perm'd
  gemm_body<1>(A, Bt, bias, o, MROWS, D_MODEL, D_MODEL, sc, tr, by * 128, bx * 128);
}

// grid (8, 64): flat f = y*8+x, nwg=512, cpx=64
__global__ __launch_bounds__(256) void gemm_f32out_kernel(
    const u16* __restrict__ A, const u16* __restrict__ Bt,
    const float* __restrict__ bias, float* __restrict__ out) {
  int f = blockIdx.y * 8 + blockIdx.x;
  int wk = xcd_swz(f, 64);
  int bx = wk & 7, by = wk >> 3;
  gemm_body<0>(A, Bt, bias, out, MROWS, D_MODEL, D_MODEL, 1.0f, 0, by * 128, bx * 128);
}

// ---------------- fused attention ----------------
// R15: KVBLK=128 — two 64-key subtiles computed per barrier period.
// Barrier+vmcnt-drain count halves (32 -> 16) and the 4 staged loads get ~2x
// the compute cycles to land before the drain. LDS 64 KB (2 blocks/CU,
// 16 waves/CU >= current ~13). Same produce/consume proof as R8: issue
// stage(g+1) at top, compute group g (both subtiles), ONE barrier.
// Everything else: 8 waves QBLK=16, gload16 staging, both-sides XOR swizzle,
// V^T pre-permuted, fixed-shift softmax, ones-MFMA lsum, cvtpk, XCD swizzle.
__global__ __launch_bounds__(512) void attn_kernel(
    const u16* __restrict__ Qb, const u16* __restrict__ Kb,
    const u16* __restrict__ Vt, u16* __restrict__ Ob) {
  __shared__ u16 Ks[2][2][64 * 64];   // [buf][sub], 32 KB total
  __shared__ u16 Vs[2][2][64 * 64];   // 32 KB total
  int tid = threadIdx.x;
  int lane = tid & 63, w = tid >> 6;            // w in [0,8)
  int l15 = lane & 15, hi = lane >> 4;
  int f = (blockIdx.z * NHEAD + blockIdx.y) * (T_SEQ / 128) + blockIdx.x;
  int wwg = xcd_swz(f, 128);              // grid 16*16*4 = 1024, cpx = 128
  int bx = wwg & 15, h = (wwg >> 4) & 15, b = wwg >> 8;
  int q0 = bx * 128 + w * 16;             // this wave's 16 q-rows
  size_t headoff = (size_t)b * T_SEQ * D_MODEL + h * DHEAD;
  const u16* vhead = Vt + (size_t)h * DHEAD * MROWS + (size_t)b * T_SEQ; // [d][t'], stride MROWS

  // Q fragments: row q0+l15, d = hf*32+hi*8
  const u16* qp = Qb + headoff + (size_t)(q0 + l15) * D_MODEL;
  bf16x8 qf0 = *(const bf16x8*)(qp + hi * 8);
  bf16x8 qf1 = *(const bf16x8*)(qp + 32 + hi * 8);

  f32x4 o[4] = {};           // o[dt]
  f32x4 lsum = {};           // ones-MFMA row-sum of P (rows equal)
  bf16x8 vones;
  { union { bf16x8 v; u16 e[8]; } c;
#pragma unroll
    for (int j = 0; j < 8; j++) c.e[j] = 0x3F80;  // bf16 1.0
    vones = c.v; }

  // staging: thread tid covers chunk tid of 512×16B per 64-key subtile;
  // row r = tid>>3, colblock cu = tid&7, source swizzled cb = cu ^ (r&7).
  int r0 = tid >> 3, cu = tid & 7;
  int cb = cu ^ (r0 & 7);
  const u16* ksrc = Kb + headoff + (size_t)r0 * D_MODEL + cb * 8;
  const u16* vsrc = vhead + (size_t)r0 * MROWS + cb * 8;   // V^T rows are d

  // prologue: key-group 0 (tiles 0,1) -> buffer 0
  gload16(ksrc,                &Ks[0][0][w * 512]);
  gload16(ksrc + 64 * D_MODEL, &Ks[0][1][w * 512]);
  gload16(vsrc,                &Vs[0][0][w * 512]);
  gload16(vsrc + 64,           &Vs[0][1][w * 512]);
  ksrc += 128 * D_MODEL; vsrc += 128;
  __syncthreads();

  const int NG = T_SEQ / 128;
  for (int g = 0; g < NG; g++) {
    int cur = g & 1;
    // issue next group's staging into the other buffer (read finished last iter)
    if (g + 1 < NG) {
      int nxt = cur ^ 1;
      gload16(ksrc,                &Ks[nxt][0][w * 512]);
      gload16(ksrc + 64 * D_MODEL, &Ks[nxt][1][w * 512]);
      gload16(vsrc,                &Vs[nxt][0][w * 512]);
      gload16(vsrc + 64,           &Vs[nxt][1][w * 512]);
      ksrc += 128 * D_MODEL; vsrc += 128;
    }

#pragma unroll
    for (int sub = 0; sub < 2; sub++) {
      // QK^T: S^T = K * Q^T (swizzled ds_read_b128 per key-quarter)
      f32x4 s[4];
      __builtin_amdgcn_s_setprio(1);
#pragma unroll
      for (int kq = 0; kq < 4; kq++) {
        int ra = kq * 16 + l15;
        bf16x8 kf0 = *(const bf16x8*)&Ks[cur][sub][ra * 64 + ((0 + hi) ^ (ra & 7)) * 8];
        bf16x8 kf1 = *(const bf16x8*)&Ks[cur][sub][ra * 64 + ((4 + hi) ^ (ra & 7)) * 8];
        f32x4 z = {};
        z = MFMA(kf0, qf0, z); z = MFMA(kf1, qf1, z);
        s[kq] = z;
      }
      __builtin_amdgcn_s_setprio(0);

      // V^T fragments (slot-ordered storage): swizzled ds_read_b128
      bf16x8 vf[4][2];
#pragma unroll
      for (int dt = 0; dt < 4; dt++) {
        int rv = dt * 16 + l15;
#pragma unroll
        for (int ks = 0; ks < 2; ks++)
          vf[dt][ks] = *(const bf16x8*)&Vs[cur][sub][rv * 64 + ((ks * 4 + hi) ^ (rv & 7)) * 8];
      }

      // fixed-shift softmax numerators: P = exp2(S')
#pragma unroll
      for (int kq = 0; kq < 4; kq++)
#pragma unroll
        for (int r = 0; r < 4; r++)
          s[kq][r] = __builtin_amdgcn_exp2f(s[kq][r]);

      // P -> bf16 B-operands; slot (hi,j) key = 32ks + 16(j>>2) + 4hi + (j&3)
      union PB { bf16x8 v; unsigned u[4]; };
      PB pb[2];
#pragma unroll
      for (int ks = 0; ks < 2; ks++) {
        pb[ks].u[0] = cvtpk(s[2*ks][0],   s[2*ks][1]);
        pb[ks].u[1] = cvtpk(s[2*ks][2],   s[2*ks][3]);
        pb[ks].u[2] = cvtpk(s[2*ks+1][0], s[2*ks+1][1]);
        pb[ks].u[3] = cvtpk(s[2*ks+1][2], s[2*ks+1][3]);
      }

      // O^T += V^T * P ; denominator lsum += ones^T * P
      __builtin_amdgcn_s_setprio(1);
#pragma unroll
      for (int ks = 0; ks < 2; ks++) {
#pragma unroll
        for (int dt = 0; dt < 4; dt++)
          o[dt] = MFMA(vf[dt][ks], pb[ks].v, o[dt]);
        lsum = MFMA(vones, pb[ks].v, lsum);
      }
      __builtin_amdgcn_s_setprio(0);
    }

    __syncthreads();   // drains vmcnt (staging) + lgkm; buffers consistent
  }

  // epilogue: l = lsum[0] (rows equal), scale, store
  float rs = 1.0f / lsum[0];
  u16* op = Ob + headoff + (size_t)(q0 + l15) * D_MODEL + hi * 4;
#pragma unroll
  for (int dt = 0; dt < 4; dt++) {
    union { u16x4 v; unsigned u[2]; } wo;
    wo.u[0] = cvtpk(o[dt][0] * rs, o[dt][1] * rs);
    wo.u[1] = cvtpk(o[dt][2] * rs, o[dt][3] * rs);
    *(u16x4*)(op + dt * 16) = wo.v;
  }
}

// ---------------- launch ----------------
extern "C" void kernel_launch(void* const* d_in, const int* in_sizes, int n_in,
                              void* d_out, int out_size, void* d_ws, size_t ws_size,
                              hipStream_t stream) {
  const float* x  = (const float*)d_in[0];
  const float* Wq = (const float*)d_in[1];
  const float* bq = (const float*)d_in[2];
  const float* Wk = (const float*)d_in[3];
  const float* bk = (const float*)d_in[4];
  const float* Wv = (const float*)d_in[5];
  const float* bv = (const float*)d_in[6];
  const float* Wo = (const float*)d_in[7];
  const float* bo = (const float*)d_in[8];

  char* ws = (char*)d_ws;
  u16* xb  = (u16*)(ws);
  u16* wqt = (u16*)(ws + ((size_t)16 << 20));
  u16* wkt = (u16*)(ws + ((size_t)18 << 20));
  u16* wvt = (u16*)(ws + ((size_t)20 << 20));
  u16* wot = (u16*)(ws + ((size_t)22 << 20));
  u16* qb  = (u16*)(ws + ((size_t)24 << 20));
  u16* kb  = (u16*)(ws + ((size_t)40 << 20));
  u16* vtb = (u16*)(ws + ((size_t)56 << 20));  // V^T [1024][8192], cols perm'd per 64
  u16* ab  = (u16*)(ws + ((size_t)72 << 20));

  cvt_x_kernel<<<(MROWS * D_MODEL / 8 + 255) / 256, 256, 0, stream>>>(x, xb, MROWS * D_MODEL / 8);
  transpose_w_kernel<<<dim3(32, 32, 4), dim3(32, 8), 0, stream>>>(Wq, Wk, Wv, Wo, wqt, wkt, wvt, wot);
  gemm_qkv_kernel<<<dim3(D_MODEL / 128, MROWS / 128, 3), 256, 0, stream>>>(
      xb, wqt, wkt, wvt, bq, bk, bv, qb, kb, vtb);
  attn_kernel<<<dim3(T_SEQ / 128, NHEAD, BATCH), 512, 0, stream>>>(qb, kb, vtb, ab);
  gemm_f32out_kernel<<<dim3(D_MODEL / 128, MROWS / 128), 256, 0, stream>>>(ab, wot, bo, (float*)d_out);
}

// Round 16
// 174.815 us; speedup vs baseline: 1.0003x; 1.0003x over previous
//
#include <hip/hip_runtime.h>
#include <hip/hip_bf16.h>

typedef unsigned short u16;
typedef u16  u16x8 __attribute__((ext_vector_type(8)));
typedef u16  u16x4 __attribute__((ext_vector_type(4)));
typedef short bf16x8 __attribute__((ext_vector_type(8)));
typedef float f32x4 __attribute__((ext_vector_type(4)));

#define D_MODEL 1024
#define T_SEQ   2048
#define BATCH   4
#define NHEAD   16
#define DHEAD   64
#define MROWS   (BATCH*T_SEQ)   /* 8192 */
#define K2LOG2E 0.18033688011112042f   /* log2(e)/sqrt(DHEAD) */

#define MFMA(a,b,c) __builtin_amdgcn_mfma_f32_16x16x32_bf16(a,b,c,0,0,0)

__device__ __forceinline__ u16 f2bf(float f) {
  __hip_bfloat16 h = __float2bfloat16(f);
  u16 r; __builtin_memcpy(&r, &h, 2); return r;
}
// v_cvt_pk_bf16_f32: low16 = bf16(lo), high16 = bf16(hi), RNE
__device__ __forceinline__ unsigned cvtpk(float lo, float hi) {
  unsigned r;
  asm("v_cvt_pk_bf16_f32 %0, %1, %2" : "=v"(r) : "v"(lo), "v"(hi));
  return r;
}

// async global -> LDS, 16B per lane (dest = wave-uniform base + lane*16)
__device__ __forceinline__ void gload16(const void* g, void* l) {
  __builtin_amdgcn_global_load_lds(
      (const __attribute__((address_space(1))) void*)g,
      (__attribute__((address_space(3))) void*)l, 16, 0, 0);
}

// T1 XCD swizzle (bijective when nwg % 8 == 0; cpx = nwg/8)
__device__ __forceinline__ int xcd_swz(int f, int cpx) {
  return (f & 7) * cpx + (f >> 3);
}

// ---------------- prep: x fp32 -> bf16 ----------------
__global__ void cvt_x_kernel(const float* __restrict__ x, u16* __restrict__ xb, int n8) {
  int i = blockIdx.x * blockDim.x + threadIdx.x;
  if (i >= n8) return;
  const f32x4* p = (const f32x4*)(x + (size_t)i * 8);
  f32x4 a = p[0], b = p[1];
  union { u16x8 v; unsigned u[4]; } o;
  o.u[0] = cvtpk(a[0], a[1]); o.u[1] = cvtpk(a[2], a[3]);
  o.u[2] = cvtpk(b[0], b[1]); o.u[3] = cvtpk(b[2], b[3]);
  *(u16x8*)(xb + (size_t)i * 8) = o.v;
}

// ---------------- prep: W [K][N] fp32 -> Wt [N][K] bf16 ----------------
// R16: 64x64 tiles, float4 loads (16B/lane), LDS [64][65] f32, u16x8 stores.
// grid (16, 16, 4), 256 threads.
__global__ void transpose_w_kernel(const float* __restrict__ w0, const float* __restrict__ w1,
                                   const float* __restrict__ w2, const float* __restrict__ w3,
                                   u16* __restrict__ o0, u16* __restrict__ o1,
                                   u16* __restrict__ o2, u16* __restrict__ o3) {
  const float* W; u16* O;
  if      (blockIdx.z == 0) { W = w0; O = o0; }
  else if (blockIdx.z == 1) { W = w1; O = o1; }
  else if (blockIdx.z == 2) { W = w2; O = o2; }
  else                      { W = w3; O = o3; }
  __shared__ float t[64][65];
  int tid = threadIdx.x;
  int k0 = blockIdx.y * 64, n0 = blockIdx.x * 64;
  // load: rows j*16 + (tid>>4), 16B per lane
  int lr = tid >> 4, lc = (tid & 15) * 4;
#pragma unroll
  for (int j = 0; j < 4; j++) {
    int row = j * 16 + lr;
    f32x4 v = *(const f32x4*)(W + (size_t)(k0 + row) * D_MODEL + n0 + lc);
    t[row][lc] = v[0]; t[row][lc + 1] = v[1]; t[row][lc + 2] = v[2]; t[row][lc + 3] = v[3];
  }
  __syncthreads();
  // store: output row n0+nr, 16 k-values (2 x u16x8) per thread
  int nr = tid >> 2, ks = (tid & 3) * 16;
  union { u16x8 v; unsigned u[4]; } a, b;
#pragma unroll
  for (int i = 0; i < 4; i++) {
    a.u[i] = cvtpk(t[ks + 2 * i][nr],     t[ks + 2 * i + 1][nr]);
    b.u[i] = cvtpk(t[ks + 8 + 2 * i][nr], t[ks + 9 + 2 * i][nr]);
  }
  u16* op = O + (size_t)(n0 + nr) * D_MODEL + k0 + ks;
  *(u16x8*)op = a.v;
  *(u16x8*)(op + 8) = b.v;
}

// ---------------- GEMM: C = (A[M,K] * Bt[N,K]^T + bias) * oscale ----------------
// R14 structure: double-buffered K-loop, stage(k+1) at iter top (gload16),
// ONE barrier per iter. BK=64, linear LDS [128][64], both-sides XOR swizzle.
// trans==0: out[m*N + n]; trans==1 (bf16): out[n*M + perm64(m)]  (V^T for attn)
template<int BF16OUT>
__device__ __forceinline__ void gemm_body(const u16* __restrict__ A, const u16* __restrict__ Bt,
                                          const float* __restrict__ bias, void* __restrict__ outp,
                                          int M, int N, int K, float oscale, int trans,
                                          int m0, int n0) {
  __shared__ u16 As[2][128 * 64];   // 32 KB
  __shared__ u16 Bs[2][128 * 64];   // 32 KB
  int tid = threadIdx.x;
  int lane = tid & 63, w = tid >> 6;
  int l15 = lane & 15, hi = lane >> 4;
  int wr = w >> 1, wc = w & 1;
  int srow = lane >> 3, su = lane & 7;
  f32x4 acc[4][4] = {};

  const u16* ap[4]; const u16* bp[4];
#pragma unroll
  for (int p = 0; p < 4; p++) {
    int row = (w * 4 + p) * 8 + srow;
    int cb  = su ^ (row & 7);
    ap[p] = A  + (size_t)(m0 + row) * K + cb * 8;
    bp[p] = Bt + (size_t)(n0 + row) * K + cb * 8;
  }

#pragma unroll
  for (int p = 0; p < 4; p++) {
    gload16(ap[p], &As[0][(w * 4 + p) * 512]);
    gload16(bp[p], &Bs[0][(w * 4 + p) * 512]);
    ap[p] += 64; bp[p] += 64;
  }
  __syncthreads();

  const int NK = K / 64;
  for (int kk = 0; kk < NK; kk++) {
    int cur = kk & 1;
    if (kk + 1 < NK) {
      int nxt = cur ^ 1;
#pragma unroll
      for (int p = 0; p < 4; p++) {
        gload16(ap[p], &As[nxt][(w * 4 + p) * 512]);
        gload16(bp[p], &Bs[nxt][(w * 4 + p) * 512]);
        ap[p] += 64; bp[p] += 64;
      }
    }
#pragma unroll
    for (int s = 0; s < 2; s++) {
      bf16x8 af[4], bfr[4];
#pragma unroll
      for (int i = 0; i < 4; i++) {
        int ra = wr * 64 + i * 16 + l15;
        af[i]  = *(const bf16x8*)&As[cur][ra * 64 + ((s * 4 + hi) ^ (ra & 7)) * 8];
        int rb = wc * 64 + i * 16 + l15;
        bfr[i] = *(const bf16x8*)&Bs[cur][rb * 64 + ((s * 4 + hi) ^ (rb & 7)) * 8];
      }
      __builtin_amdgcn_s_setprio(1);
#pragma unroll
      for (int i = 0; i < 4; i++)
#pragma unroll
        for (int j = 0; j < 4; j++)
          acc[i][j] = MFMA(af[i], bfr[j], acc[i][j]);
      __builtin_amdgcn_s_setprio(0);
    }
    __syncthreads();
  }

  // C/D layout: col = lane&15, row = (lane>>4)*4 + reg
  if (trans) {
#pragma unroll
    for (int j = 0; j < 4; j++) {
      int n = n0 + wc * 64 + j * 16 + l15;
      float bv = bias[n];
#pragma unroll
      for (int i = 0; i < 4; i++) {
        int mb = m0 + wr * 64 + i * 16 + hi * 4;
        int off = mb & 63;
        int colp = (off & 32) + (((off >> 2) & 3) << 3) + (((off >> 4) & 1) << 2);
        union { u16x4 v; unsigned u[2]; } t;
        t.u[0] = cvtpk((acc[i][j][0] + bv) * oscale, (acc[i][j][1] + bv) * oscale);
        t.u[1] = cvtpk((acc[i][j][2] + bv) * oscale, (acc[i][j][3] + bv) * oscale);
        *(u16x4*)((u16*)outp + (size_t)n * M + (mb - off) + colp) = t.v;
      }
    }
  } else {
#pragma unroll
    for (int j = 0; j < 4; j++) {
      int n = n0 + wc * 64 + j * 16 + l15;
      float bv = bias[n];
#pragma unroll
      for (int i = 0; i < 4; i++) {
        int mbase = m0 + wr * 64 + i * 16 + hi * 4;
#pragma unroll
        for (int r = 0; r < 4; r++) {
          float v = (acc[i][j][r] + bv) * oscale;
          if (BF16OUT) ((u16*)outp)[(size_t)(mbase + r) * N + n] = f2bf(v);
          else        ((float*)outp)[(size_t)(mbase + r) * N + n] = v;
        }
      }
    }
  }
}

// grid (8, 64, 3): flat f = (z*64+y)*8+x, nwg=1536, cpx=192
__global__ __launch_bounds__(256) void gemm_qkv_kernel(
    const u16* __restrict__ A,
    const u16* __restrict__ Btq, const u16* __restrict__ Btk, const u16* __restrict__ Btv,
    const float* __restrict__ bq, const float* __restrict__ bk, const float* __restrict__ bv,
    u16* __restrict__ oq, u16* __restrict__ ok, u16* __restrict__ ov) {
  int f = (blockIdx.z * 64 + blockIdx.y) * 8 + blockIdx.x;
  int wk = xcd_swz(f, 192);
  int bx = wk & 7, by = (wk >> 3) & 63, bz = wk >> 9;
  const u16* Bt; const float* bias; u16* o; float sc; int tr;
  if      (bz == 0) { Bt = Btq; bias = bq; o = oq; sc = K2LOG2E; tr = 0; }  // Q pre-scaled
  else if (bz == 1) { Bt = Btk; bias = bk; o = ok; sc = 1.0f; tr = 0; }
  else              { Bt = Btv; bias = bv; o = ov; sc = 1.0f; tr = 1; }     // V^T, perm'd
  gemm_body<1>(A, Bt, bias, o, MROWS, D_MODEL, D_MODEL, sc, tr, by * 128, bx * 128);
}

// grid (8, 64): flat f = y*8+x, nwg=512, cpx=64
__global__ __launch_bounds__(256) void gemm_f32out_kernel(
    const u16* __restrict__ A, const u16* __restrict__ Bt,
    const float* __restrict__ bias, float* __restrict__ out) {
  int f = blockIdx.y * 8 + blockIdx.x;
  int wk = xcd_swz(f, 64);
  int bx = wk & 7, by = wk >> 3;
  gemm_body<0>(A, Bt, bias, out, MROWS, D_MODEL, D_MODEL, 1.0f, 0, by * 128, bx * 128);
}

// ---------------- fused attention ----------------
// R16: depth-2 staging pipeline with counted vmcnt (T4). KVBLK=64, THREE
// K/V buffers (48 KB -> 3 blocks/CU = 24 waves/CU). Per iter t:
//   stage(t+2) -> buf[(t+2)%3]; compute(t) from buf[t%3];
//   s_waitcnt vmcnt(2)  (waits only stage(t+1)'s 2 loads — never drains the
//   just-issued pair); raw s_barrier; sched_barrier(0) seals the gap (a
//   ds_read must not slide between wait and barrier: each wave's vmcnt only
//   proves ITS OWN chunk landed).
// Buffer safety: write target (t+2)%3 differs from read buffers t%3,(t+1)%3;
// the overwrite of (t-1)%3 is issued only after the barrier all waves reached
// post-read. Components kept: 8 waves QBLK=16, gload16, both-sides XOR
// swizzle, V^T pre-permuted, fixed-shift softmax, ones-MFMA lsum, cvtpk, T1.
__global__ __launch_bounds__(512) void attn_kernel(
    const u16* __restrict__ Qb, const u16* __restrict__ Kb,
    const u16* __restrict__ Vt, u16* __restrict__ Ob) {
  __shared__ u16 Ks[3][64 * 64];   // 24 KB
  __shared__ u16 Vs[3][64 * 64];   // 24 KB
  int tid = threadIdx.x;
  int lane = tid & 63, w = tid >> 6;            // w in [0,8)
  int l15 = lane & 15, hi = lane >> 4;
  int f = (blockIdx.z * NHEAD + blockIdx.y) * (T_SEQ / 128) + blockIdx.x;
  int wwg = xcd_swz(f, 128);              // grid 16*16*4 = 1024, cpx = 128
  int bx = wwg & 15, h = (wwg >> 4) & 15, b = wwg >> 8;
  int q0 = bx * 128 + w * 16;             // this wave's 16 q-rows
  size_t headoff = (size_t)b * T_SEQ * D_MODEL + h * DHEAD;
  const u16* vhead = Vt + (size_t)h * DHEAD * MROWS + (size_t)b * T_SEQ;

  // Q fragments: row q0+l15, d = hf*32+hi*8
  const u16* qp = Qb + headoff + (size_t)(q0 + l15) * D_MODEL;
  bf16x8 qf0 = *(const bf16x8*)(qp + hi * 8);
  bf16x8 qf1 = *(const bf16x8*)(qp + 32 + hi * 8);

  f32x4 o[4] = {};           // o[dt]
  f32x4 lsum = {};           // ones-MFMA row-sum of P (rows equal)
  bf16x8 vones;
  { union { bf16x8 v; u16 e[8]; } c;
#pragma unroll
    for (int j = 0; j < 8; j++) c.e[j] = 0x3F80;  // bf16 1.0
    vones = c.v; }

  // staging: thread tid covers chunk tid of 512×16B per tile;
  // row r = tid>>3, colblock cu = tid&7, source swizzled cb = cu ^ (r&7).
  int r0 = tid >> 3, cu = tid & 7;
  int cb = cu ^ (r0 & 7);
  const u16* ksrc = Kb + headoff + (size_t)r0 * D_MODEL + cb * 8;
  const u16* vsrc = vhead + (size_t)r0 * MROWS + cb * 8;   // V^T rows are d

  // prologue: tiles 0,1 -> buffers 0,1 (2 loads each)
  gload16(ksrc, &Ks[0][w * 512]);
  gload16(vsrc, &Vs[0][w * 512]);
  ksrc += 64 * D_MODEL; vsrc += 64;
  gload16(ksrc, &Ks[1][w * 512]);
  gload16(vsrc, &Vs[1][w * 512]);
  ksrc += 64 * D_MODEL; vsrc += 64;
  asm volatile("s_waitcnt vmcnt(2)" ::: "memory");   // tile 0 landed
  __builtin_amdgcn_s_barrier();
  __builtin_amdgcn_sched_barrier(0);

  const int NT = T_SEQ / 64;   // 32
  int bufc = 0, bufs = 2;
  for (int t = 0; t < NT; t++) {
    // issue stage(t+2) into buf[(t+2)%3]
    if (t + 2 < NT) {
      gload16(ksrc, &Ks[bufs][w * 512]);
      gload16(vsrc, &Vs[bufs][w * 512]);
      ksrc += 64 * D_MODEL; vsrc += 64;
    }
    const u16* kb_ = &Ks[bufc][0];
    const u16* vb_ = &Vs[bufc][0];

    // QK^T: S^T = K * Q^T (swizzled ds_read_b128 per key-subtile)
    f32x4 s[4];
    __builtin_amdgcn_s_setprio(1);
#pragma unroll
    for (int sub = 0; sub < 4; sub++) {
      int ra = sub * 16 + l15;
      bf16x8 kf0 = *(const bf16x8*)&kb_[ra * 64 + ((0 + hi) ^ (ra & 7)) * 8];
      bf16x8 kf1 = *(const bf16x8*)&kb_[ra * 64 + ((4 + hi) ^ (ra & 7)) * 8];
      f32x4 z = {};
      z = MFMA(kf0, qf0, z); z = MFMA(kf1, qf1, z);
      s[sub] = z;
    }
    __builtin_amdgcn_s_setprio(0);

    // V^T fragments (slot-ordered storage): swizzled ds_read_b128
    bf16x8 vf[4][2];
#pragma unroll
    for (int dt = 0; dt < 4; dt++) {
      int rv = dt * 16 + l15;
#pragma unroll
      for (int ks = 0; ks < 2; ks++)
        vf[dt][ks] = *(const bf16x8*)&vb_[rv * 64 + ((ks * 4 + hi) ^ (rv & 7)) * 8];
    }

    // fixed-shift softmax numerators: P = exp2(S')
#pragma unroll
    for (int sub = 0; sub < 4; sub++)
#pragma unroll
      for (int r = 0; r < 4; r++)
        s[sub][r] = __builtin_amdgcn_exp2f(s[sub][r]);

    // P -> bf16 B-operands; slot (hi,j) key = 32ks + 16(j>>2) + 4hi + (j&3)
    union PB { bf16x8 v; unsigned u[4]; };
    PB pb[2];
#pragma unroll
    for (int ks = 0; ks < 2; ks++) {
      pb[ks].u[0] = cvtpk(s[2*ks][0],   s[2*ks][1]);
      pb[ks].u[1] = cvtpk(s[2*ks][2],   s[2*ks][3]);
      pb[ks].u[2] = cvtpk(s[2*ks+1][0], s[2*ks+1][1]);
      pb[ks].u[3] = cvtpk(s[2*ks+1][2], s[2*ks+1][3]);
    }

    // O^T += V^T * P ; denominator lsum += ones^T * P
    __builtin_amdgcn_s_setprio(1);
#pragma unroll
    for (int ks = 0; ks < 2; ks++) {
#pragma unroll
      for (int dt = 0; dt < 4; dt++)
        o[dt] = MFMA(vf[dt][ks], pb[ks].v, o[dt]);
      lsum = MFMA(vones, pb[ks].v, lsum);
    }
    __builtin_amdgcn_s_setprio(0);

    // counted wait: stage(t+1) landed (2 oldest of <=4 outstanding); barrier
    if (t + 2 < NT) {
      asm volatile("s_waitcnt vmcnt(2)" ::: "memory");
    } else {
      asm volatile("s_waitcnt vmcnt(0)" ::: "memory");
    }
    __builtin_amdgcn_s_barrier();
    __builtin_amdgcn_sched_barrier(0);

    bufc = (bufc == 2) ? 0 : bufc + 1;
    bufs = (bufs == 2) ? 0 : bufs + 1;
  }

  // epilogue: l = lsum[0] (rows equal), scale, store
  float rs = 1.0f / lsum[0];
  u16* op = Ob + headoff + (size_t)(q0 + l15) * D_MODEL + hi * 4;
#pragma unroll
  for (int dt = 0; dt < 4; dt++) {
    union { u16x4 v; unsigned u[2]; } wo;
    wo.u[0] = cvtpk(o[dt][0] * rs, o[dt][1] * rs);
    wo.u[1] = cvtpk(o[dt][2] * rs, o[dt][3] * rs);
    *(u16x4*)(op + dt * 16) = wo.v;
  }
}

// ---------------- launch ----------------
extern "C" void kernel_launch(void* const* d_in, const int* in_sizes, int n_in,
                              void* d_out, int out_size, void* d_ws, size_t ws_size,
                              hipStream_t stream) {
  const float* x  = (const float*)d_in[0];
  const float* Wq = (const float*)d_in[1];
  const float* bq = (const float*)d_in[2];
  const float* Wk = (const float*)d_in[3];
  const float* bk = (const float*)d_in[4];
  const float* Wv = (const float*)d_in[5];
  const float* bv = (const float*)d_in[6];
  const float* Wo = (const float*)d_in[7];
  const float* bo = (const float*)d_in[8];

  char* ws = (char*)d_ws;
  u16* xb  = (u16*)(ws);
  u16* wqt = (u16*)(ws + ((size_t)16 << 20));
  u16* wkt = (u16*)(ws + ((size_t)18 << 20));
  u16* wvt = (u16*)(ws + ((size_t)20 << 20));
  u16* wot = (u16*)(ws + ((size_t)22 << 20));
  u16* qb  = (u16*)(ws + ((size_t)24 << 20));
  u16* kb  = (u16*)(ws + ((size_t)40 << 20));
  u16* vtb = (u16*)(ws + ((size_t)56 << 20));  // V^T [1024][8192], cols perm'd per 64
  u16* ab  = (u16*)(ws + ((size_t)72 << 20));

  cvt_x_kernel<<<(MROWS * D_MODEL / 8 + 255) / 256, 256, 0, stream>>>(x, xb, MROWS * D_MODEL / 8);
  transpose_w_kernel<<<dim3(16, 16, 4), 256, 0, stream>>>(Wq, Wk, Wv, Wo, wqt, wkt, wvt, wot);
  gemm_qkv_kernel<<<dim3(D_MODEL / 128, MROWS / 128, 3), 256, 0, stream>>>(
      xb, wqt, wkt, wvt, bq, bk, bv, qb, kb, vtb);
  attn_kernel<<<dim3(T_SEQ / 128, NHEAD, BATCH), 512, 0, stream>>>(qb, kb, vtb, ab);
  gemm_f32out_kernel<<<dim3(D_MODEL / 128, MROWS / 128), 256, 0, stream>>>(ab, wot, bo, (float*)d_out);
}

// Round 17
// 172.853 us; speedup vs baseline: 1.0117x; 1.0114x over previous
//
#include <hip/hip_runtime.h>
#include <hip/hip_bf16.h>

typedef unsigned short u16;
typedef u16  u16x8 __attribute__((ext_vector_type(8)));
typedef u16  u16x4 __attribute__((ext_vector_type(4)));
typedef short bf16x8 __attribute__((ext_vector_type(8)));
typedef float f32x4 __attribute__((ext_vector_type(4)));

#define D_MODEL 1024
#define T_SEQ   2048
#define BATCH   4
#define NHEAD   16
#define DHEAD   64
#define MROWS   (BATCH*T_SEQ)   /* 8192 */
#define K2LOG2E 0.18033688011112042f   /* log2(e)/sqrt(DHEAD) */

#define MFMA(a,b,c) __builtin_amdgcn_mfma_f32_16x16x32_bf16(a,b,c,0,0,0)

__device__ __forceinline__ u16 f2bf(float f) {
  __hip_bfloat16 h = __float2bfloat16(f);
  u16 r; __builtin_memcpy(&r, &h, 2); return r;
}
// v_cvt_pk_bf16_f32: low16 = bf16(lo), high16 = bf16(hi), RNE
__device__ __forceinline__ unsigned cvtpk(float lo, float hi) {
  unsigned r;
  asm("v_cvt_pk_bf16_f32 %0, %1, %2" : "=v"(r) : "v"(lo), "v"(hi));
  return r;
}

// async global -> LDS, 16B per lane (dest = wave-uniform base + lane*16)
__device__ __forceinline__ void gload16(const void* g, void* l) {
  __builtin_amdgcn_global_load_lds(
      (const __attribute__((address_space(1))) void*)g,
      (__attribute__((address_space(3))) void*)l, 16, 0, 0);
}

// T1 XCD swizzle (bijective when nwg % 8 == 0; cpx = nwg/8)
__device__ __forceinline__ int xcd_swz(int f, int cpx) {
  return (f & 7) * cpx + (f >> 3);
}

// ---------------- prep: x fp32 -> bf16 ----------------
__global__ void cvt_x_kernel(const float* __restrict__ x, u16* __restrict__ xb, int n8) {
  int i = blockIdx.x * blockDim.x + threadIdx.x;
  if (i >= n8) return;
  const f32x4* p = (const f32x4*)(x + (size_t)i * 8);
  f32x4 a = p[0], b = p[1];
  union { u16x8 v; unsigned u[4]; } o;
  o.u[0] = cvtpk(a[0], a[1]); o.u[1] = cvtpk(a[2], a[3]);
  o.u[2] = cvtpk(b[0], b[1]); o.u[3] = cvtpk(b[2], b[3]);
  *(u16x8*)(xb + (size_t)i * 8) = o.v;
}

// ---------------- prep: W [K][N] fp32 -> Wt [N][K] bf16 ----------------
// R16: 64x64 tiles, float4 loads (16B/lane), LDS [64][65] f32, u16x8 stores.
// grid (16, 16, 4), 256 threads.
__global__ void transpose_w_kernel(const float* __restrict__ w0, const float* __restrict__ w1,
                                   const float* __restrict__ w2, const float* __restrict__ w3,
                                   u16* __restrict__ o0, u16* __restrict__ o1,
                                   u16* __restrict__ o2, u16* __restrict__ o3) {
  const float* W; u16* O;
  if      (blockIdx.z == 0) { W = w0; O = o0; }
  else if (blockIdx.z == 1) { W = w1; O = o1; }
  else if (blockIdx.z == 2) { W = w2; O = o2; }
  else                      { W = w3; O = o3; }
  __shared__ float t[64][65];
  int tid = threadIdx.x;
  int k0 = blockIdx.y * 64, n0 = blockIdx.x * 64;
  int lr = tid >> 4, lc = (tid & 15) * 4;
#pragma unroll
  for (int j = 0; j < 4; j++) {
    int row = j * 16 + lr;
    f32x4 v = *(const f32x4*)(W + (size_t)(k0 + row) * D_MODEL + n0 + lc);
    t[row][lc] = v[0]; t[row][lc + 1] = v[1]; t[row][lc + 2] = v[2]; t[row][lc + 3] = v[3];
  }
  __syncthreads();
  int nr = tid >> 2, ks = (tid & 3) * 16;
  union { u16x8 v; unsigned u[4]; } a, b;
#pragma unroll
  for (int i = 0; i < 4; i++) {
    a.u[i] = cvtpk(t[ks + 2 * i][nr],     t[ks + 2 * i + 1][nr]);
    b.u[i] = cvtpk(t[ks + 8 + 2 * i][nr], t[ks + 9 + 2 * i][nr]);
  }
  u16* op = O + (size_t)(n0 + nr) * D_MODEL + k0 + ks;
  *(u16x8*)op = a.v;
  *(u16x8*)(op + 8) = b.v;
}

// ---------------- GEMM: C = (A[M,K] * Bt[N,K]^T + bias) * oscale ----------------
// R14 structure: double-buffered K-loop, stage(k+1) at iter top (gload16),
// ONE barrier per iter. BK=64, linear LDS [128][64], both-sides XOR swizzle.
// trans==0: out[m*N + n]; trans==1 (bf16): out[n*M + perm64(m)]  (V^T for attn)
template<int BF16OUT>
__device__ __forceinline__ void gemm_body(const u16* __restrict__ A, const u16* __restrict__ Bt,
                                          const float* __restrict__ bias, void* __restrict__ outp,
                                          int M, int N, int K, float oscale, int trans,
                                          int m0, int n0) {
  __shared__ u16 As[2][128 * 64];   // 32 KB
  __shared__ u16 Bs[2][128 * 64];   // 32 KB
  int tid = threadIdx.x;
  int lane = tid & 63, w = tid >> 6;
  int l15 = lane & 15, hi = lane >> 4;
  int wr = w >> 1, wc = w & 1;
  int srow = lane >> 3, su = lane & 7;
  f32x4 acc[4][4] = {};

  const u16* ap[4]; const u16* bp[4];
#pragma unroll
  for (int p = 0; p < 4; p++) {
    int row = (w * 4 + p) * 8 + srow;
    int cb  = su ^ (row & 7);
    ap[p] = A  + (size_t)(m0 + row) * K + cb * 8;
    bp[p] = Bt + (size_t)(n0 + row) * K + cb * 8;
  }

#pragma unroll
  for (int p = 0; p < 4; p++) {
    gload16(ap[p], &As[0][(w * 4 + p) * 512]);
    gload16(bp[p], &Bs[0][(w * 4 + p) * 512]);
    ap[p] += 64; bp[p] += 64;
  }
  __syncthreads();

  const int NK = K / 64;
  for (int kk = 0; kk < NK; kk++) {
    int cur = kk & 1;
    if (kk + 1 < NK) {
      int nxt = cur ^ 1;
#pragma unroll
      for (int p = 0; p < 4; p++) {
        gload16(ap[p], &As[nxt][(w * 4 + p) * 512]);
        gload16(bp[p], &Bs[nxt][(w * 4 + p) * 512]);
        ap[p] += 64; bp[p] += 64;
      }
    }
#pragma unroll
    for (int s = 0; s < 2; s++) {
      bf16x8 af[4], bfr[4];
#pragma unroll
      for (int i = 0; i < 4; i++) {
        int ra = wr * 64 + i * 16 + l15;
        af[i]  = *(const bf16x8*)&As[cur][ra * 64 + ((s * 4 + hi) ^ (ra & 7)) * 8];
        int rb = wc * 64 + i * 16 + l15;
        bfr[i] = *(const bf16x8*)&Bs[cur][rb * 64 + ((s * 4 + hi) ^ (rb & 7)) * 8];
      }
      __builtin_amdgcn_s_setprio(1);
#pragma unroll
      for (int i = 0; i < 4; i++)
#pragma unroll
        for (int j = 0; j < 4; j++)
          acc[i][j] = MFMA(af[i], bfr[j], acc[i][j]);
      __builtin_amdgcn_s_setprio(0);
    }
    __syncthreads();
  }

  // C/D layout: col = lane&15, row = (lane>>4)*4 + reg
  if (trans) {
#pragma unroll
    for (int j = 0; j < 4; j++) {
      int n = n0 + wc * 64 + j * 16 + l15;
      float bv = bias[n];
#pragma unroll
      for (int i = 0; i < 4; i++) {
        int mb = m0 + wr * 64 + i * 16 + hi * 4;
        int off = mb & 63;
        int colp = (off & 32) + (((off >> 2) & 3) << 3) + (((off >> 4) & 1) << 2);
        union { u16x4 v; unsigned u[2]; } t;
        t.u[0] = cvtpk((acc[i][j][0] + bv) * oscale, (acc[i][j][1] + bv) * oscale);
        t.u[1] = cvtpk((acc[i][j][2] + bv) * oscale, (acc[i][j][3] + bv) * oscale);
        *(u16x4*)((u16*)outp + (size_t)n * M + (mb - off) + colp) = t.v;
      }
    }
  } else {
#pragma unroll
    for (int j = 0; j < 4; j++) {
      int n = n0 + wc * 64 + j * 16 + l15;
      float bv = bias[n];
#pragma unroll
      for (int i = 0; i < 4; i++) {
        int mbase = m0 + wr * 64 + i * 16 + hi * 4;
#pragma unroll
        for (int r = 0; r < 4; r++) {
          float v = (acc[i][j][r] + bv) * oscale;
          if (BF16OUT) ((u16*)outp)[(size_t)(mbase + r) * N + n] = f2bf(v);
          else        ((float*)outp)[(size_t)(mbase + r) * N + n] = v;
        }
      }
    }
  }
}

// grid (8, 64, 3): flat f = (z*64+y)*8+x, nwg=1536, cpx=192
__global__ __launch_bounds__(256) void gemm_qkv_kernel(
    const u16* __restrict__ A,
    const u16* __restrict__ Btq, const u16* __restrict__ Btk, const u16* __restrict__ Btv,
    const float* __restrict__ bq, const float* __restrict__ bk, const float* __restrict__ bv,
    u16* __restrict__ oq, u16* __restrict__ ok, u16* __restrict__ ov) {
  int f = (blockIdx.z * 64 + blockIdx.y) * 8 + blockIdx.x;
  int wk = xcd_swz(f, 192);
  int bx = wk & 7, by = (wk >> 3) & 63, bz = wk >> 9;
  const u16* Bt; const float* bias; u16* o; float sc; int tr;
  if      (bz == 0) { Bt = Btq; bias = bq; o = oq; sc = K2LOG2E; tr = 0; }  // Q pre-scaled
  else if (bz == 1) { Bt = Btk; bias = bk; o = ok; sc = 1.0f; tr = 0; }
  else              { Bt = Btv; bias = bv; o = ov; sc = 1.0f; tr = 1; }     // V^T, perm'd
  gemm_body<1>(A, Bt, bias, o, MROWS, D_MODEL, D_MODEL, sc, tr, by * 128, bx * 128);
}

// grid (8, 64): flat f = y*8+x, nwg=512, cpx=64
__global__ __launch_bounds__(256) void gemm_f32out_kernel(
    const u16* __restrict__ A, const u16* __restrict__ Bt,
    const float* __restrict__ bias, float* __restrict__ out) {
  int f = blockIdx.y * 8 + blockIdx.x;
  int wk = xcd_swz(f, 64);
  int bx = wk & 7, by = wk >> 3;
  gemm_body<0>(A, Bt, bias, out, MROWS, D_MODEL, D_MODEL, 1.0f, 0, by * 128, bx * 128);
}

// ---------------- fused attention (R15 — best measured: 78.9 µs) ----------------
// KVBLK=128: two 64-key subtiles per barrier period; double-buffered (64 KB).
// stage(g+1) issued at top, compute both subtiles of group g, ONE barrier.
// 8 waves QBLK=16, gload16 staging, both-sides XOR swizzle, V^T pre-permuted,
// fixed-shift softmax, ones-MFMA lsum, cvtpk packs, T1 XCD swizzle.
__global__ __launch_bounds__(512) void attn_kernel(
    const u16* __restrict__ Qb, const u16* __restrict__ Kb,
    const u16* __restrict__ Vt, u16* __restrict__ Ob) {
  __shared__ u16 Ks[2][2][64 * 64];   // [buf][sub], 32 KB total
  __shared__ u16 Vs[2][2][64 * 64];   // 32 KB total
  int tid = threadIdx.x;
  int lane = tid & 63, w = tid >> 6;            // w in [0,8)
  int l15 = lane & 15, hi = lane >> 4;
  int f = (blockIdx.z * NHEAD + blockIdx.y) * (T_SEQ / 128) + blockIdx.x;
  int wwg = xcd_swz(f, 128);              // grid 16*16*4 = 1024, cpx = 128
  int bx = wwg & 15, h = (wwg >> 4) & 15, b = wwg >> 8;
  int q0 = bx * 128 + w * 16;             // this wave's 16 q-rows
  size_t headoff = (size_t)b * T_SEQ * D_MODEL + h * DHEAD;
  const u16* vhead = Vt + (size_t)h * DHEAD * MROWS + (size_t)b * T_SEQ; // [d][t'], stride MROWS

  // Q fragments: row q0+l15, d = hf*32+hi*8
  const u16* qp = Qb + headoff + (size_t)(q0 + l15) * D_MODEL;
  bf16x8 qf0 = *(const bf16x8*)(qp + hi * 8);
  bf16x8 qf1 = *(const bf16x8*)(qp + 32 + hi * 8);

  f32x4 o[4] = {};           // o[dt]
  f32x4 lsum = {};           // ones-MFMA row-sum of P (rows equal)
  bf16x8 vones;
  { union { bf16x8 v; u16 e[8]; } c;
#pragma unroll
    for (int j = 0; j < 8; j++) c.e[j] = 0x3F80;  // bf16 1.0
    vones = c.v; }

  // staging: thread tid covers chunk tid of 512×16B per 64-key subtile;
  // row r = tid>>3, colblock cu = tid&7, source swizzled cb = cu ^ (r&7).
  int r0 = tid >> 3, cu = tid & 7;
  int cb = cu ^ (r0 & 7);
  const u16* ksrc = Kb + headoff + (size_t)r0 * D_MODEL + cb * 8;
  const u16* vsrc = vhead + (size_t)r0 * MROWS + cb * 8;   // V^T rows are d

  // prologue: key-group 0 (tiles 0,1) -> buffer 0
  gload16(ksrc,                &Ks[0][0][w * 512]);
  gload16(ksrc + 64 * D_MODEL, &Ks[0][1][w * 512]);
  gload16(vsrc,                &Vs[0][0][w * 512]);
  gload16(vsrc + 64,           &Vs[0][1][w * 512]);
  ksrc += 128 * D_MODEL; vsrc += 128;
  __syncthreads();

  const int NG = T_SEQ / 128;
  for (int g = 0; g < NG; g++) {
    int cur = g & 1;
    // issue next group's staging into the other buffer (read finished last iter)
    if (g + 1 < NG) {
      int nxt = cur ^ 1;
      gload16(ksrc,                &Ks[nxt][0][w * 512]);
      gload16(ksrc + 64 * D_MODEL, &Ks[nxt][1][w * 512]);
      gload16(vsrc,                &Vs[nxt][0][w * 512]);
      gload16(vsrc + 64,           &Vs[nxt][1][w * 512]);
      ksrc += 128 * D_MODEL; vsrc += 128;
    }

#pragma unroll
    for (int sub = 0; sub < 2; sub++) {
      // QK^T: S^T = K * Q^T (swizzled ds_read_b128 per key-quarter)
      f32x4 s[4];
      __builtin_amdgcn_s_setprio(1);
#pragma unroll
      for (int kq = 0; kq < 4; kq++) {
        int ra = kq * 16 + l15;
        bf16x8 kf0 = *(const bf16x8*)&Ks[cur][sub][ra * 64 + ((0 + hi) ^ (ra & 7)) * 8];
        bf16x8 kf1 = *(const bf16x8*)&Ks[cur][sub][ra * 64 + ((4 + hi) ^ (ra & 7)) * 8];
        f32x4 z = {};
        z = MFMA(kf0, qf0, z); z = MFMA(kf1, qf1, z);
        s[kq] = z;
      }
      __builtin_amdgcn_s_setprio(0);

      // V^T fragments (slot-ordered storage): swizzled ds_read_b128
      bf16x8 vf[4][2];
#pragma unroll
      for (int dt = 0; dt < 4; dt++) {
        int rv = dt * 16 + l15;
#pragma unroll
        for (int ks = 0; ks < 2; ks++)
          vf[dt][ks] = *(const bf16x8*)&Vs[cur][sub][rv * 64 + ((ks * 4 + hi) ^ (rv & 7)) * 8];
      }

      // fixed-shift softmax numerators: P = exp2(S')
#pragma unroll
      for (int kq = 0; kq < 4; kq++)
#pragma unroll
        for (int r = 0; r < 4; r++)
          s[kq][r] = __builtin_amdgcn_exp2f(s[kq][r]);

      // P -> bf16 B-operands; slot (hi,j) key = 32ks + 16(j>>2) + 4hi + (j&3)
      union PB { bf16x8 v; unsigned u[4]; };
      PB pb[2];
#pragma unroll
      for (int ks = 0; ks < 2; ks++) {
        pb[ks].u[0] = cvtpk(s[2*ks][0],   s[2*ks][1]);
        pb[ks].u[1] = cvtpk(s[2*ks][2],   s[2*ks][3]);
        pb[ks].u[2] = cvtpk(s[2*ks+1][0], s[2*ks+1][1]);
        pb[ks].u[3] = cvtpk(s[2*ks+1][2], s[2*ks+1][3]);
      }

      // O^T += V^T * P ; denominator lsum += ones^T * P
      __builtin_amdgcn_s_setprio(1);
#pragma unroll
      for (int ks = 0; ks < 2; ks++) {
#pragma unroll
        for (int dt = 0; dt < 4; dt++)
          o[dt] = MFMA(vf[dt][ks], pb[ks].v, o[dt]);
        lsum = MFMA(vones, pb[ks].v, lsum);
      }
      __builtin_amdgcn_s_setprio(0);
    }

    __syncthreads();   // drains vmcnt (staging) + lgkm; buffers consistent
  }

  // epilogue: l = lsum[0] (rows equal), scale, store
  float rs = 1.0f / lsum[0];
  u16* op = Ob + headoff + (size_t)(q0 + l15) * D_MODEL + hi * 4;
#pragma unroll
  for (int dt = 0; dt < 4; dt++) {
    union { u16x4 v; unsigned u[2]; } wo;
    wo.u[0] = cvtpk(o[dt][0] * rs, o[dt][1] * rs);
    wo.u[1] = cvtpk(o[dt][2] * rs, o[dt][3] * rs);
    *(u16x4*)(op + dt * 16) = wo.v;
  }
}

// ---------------- launch ----------------
extern "C" void kernel_launch(void* const* d_in, const int* in_sizes, int n_in,
                              void* d_out, int out_size, void* d_ws, size_t ws_size,
                              hipStream_t stream) {
  const float* x  = (const float*)d_in[0];
  const float* Wq = (const float*)d_in[1];
  const float* bq = (const float*)d_in[2];
  const float* Wk = (const float*)d_in[3];
  const float* bk = (const float*)d_in[4];
  const float* Wv = (const float*)d_in[5];
  const float* bv = (const float*)d_in[6];
  const float* Wo = (const float*)d_in[7];
  const float* bo = (const float*)d_in[8];

  char* ws = (char*)d_ws;
  u16* xb  = (u16*)(ws);
  u16* wqt = (u16*)(ws + ((size_t)16 << 20));
  u16* wkt = (u16*)(ws + ((size_t)18 << 20));
  u16* wvt = (u16*)(ws + ((size_t)20 << 20));
  u16* wot = (u16*)(ws + ((size_t)22 << 20));
  u16* qb  = (u16*)(ws + ((size_t)24 << 20));
  u16* kb  = (u16*)(ws + ((size_t)40 << 20));
  u16* vtb = (u16*)(ws + ((size_t)56 << 20));  // V^T [1024][8192], cols perm'd per 64
  u16* ab  = (u16*)(ws + ((size_t)72 << 20));

  cvt_x_kernel<<<(MROWS * D_MODEL / 8 + 255) / 256, 256, 0, stream>>>(x, xb, MROWS * D_MODEL / 8);
  transpose_w_kernel<<<dim3(16, 16, 4), 256, 0, stream>>>(Wq, Wk, Wv, Wo, wqt, wkt, wvt, wot);
  gemm_qkv_kernel<<<dim3(D_MODEL / 128, MROWS / 128, 3), 256, 0, stream>>>(
      xb, wqt, wkt, wvt, bq, bk, bv, qb, kb, vtb);
  attn_kernel<<<dim3(T_SEQ / 128, NHEAD, BATCH), 512, 0, stream>>>(qb, kb, vtb, ab);
  gemm_f32out_kernel<<<dim3(D_MODEL / 128, MROWS / 128), 256, 0, stream>>>(ab, wot, bo, (float*)d_out);
}

// Round 18
// 164.792 us; speedup vs baseline: 1.0612x; 1.0489x over previous
//
#include <hip/hip_runtime.h>
#include <hip/hip_bf16.h>

typedef unsigned short u16;
typedef u16  u16x8 __attribute__((ext_vector_type(8)));
typedef u16  u16x4 __attribute__((ext_vector_type(4)));
typedef short bf16x8 __attribute__((ext_vector_type(8)));
typedef float f32x4 __attribute__((ext_vector_type(4)));

#define D_MODEL 1024
#define T_SEQ   2048
#define BATCH   4
#define NHEAD   16
#define DHEAD   64
#define MROWS   (BATCH*T_SEQ)   /* 8192 */
#define K2LOG2E 0.18033688011112042f   /* log2(e)/sqrt(DHEAD) */

#define MFMA(a,b,c) __builtin_amdgcn_mfma_f32_16x16x32_bf16(a,b,c,0,0,0)

__device__ __forceinline__ u16 f2bf(float f) {
  __hip_bfloat16 h = __float2bfloat16(f);
  u16 r; __builtin_memcpy(&r, &h, 2); return r;
}
// v_cvt_pk_bf16_f32: low16 = bf16(lo), high16 = bf16(hi), RNE
__device__ __forceinline__ unsigned cvtpk(float lo, float hi) {
  unsigned r;
  asm("v_cvt_pk_bf16_f32 %0, %1, %2" : "=v"(r) : "v"(lo), "v"(hi));
  return r;
}

// async global -> LDS, 16B per lane (dest = wave-uniform base + lane*16)
__device__ __forceinline__ void gload16(const void* g, void* l) {
  __builtin_amdgcn_global_load_lds(
      (const __attribute__((address_space(1))) void*)g,
      (__attribute__((address_space(3))) void*)l, 16, 0, 0);
}

// T1 XCD swizzle (bijective when nwg % 8 == 0; cpx = nwg/8)
__device__ __forceinline__ int xcd_swz(int f, int cpx) {
  return (f & 7) * cpx + (f >> 3);
}

// ---------------- prep: x fp32 -> bf16 ----------------
__global__ void cvt_x_kernel(const float* __restrict__ x, u16* __restrict__ xb, int n8) {
  int i = blockIdx.x * blockDim.x + threadIdx.x;
  if (i >= n8) return;
  const f32x4* p = (const f32x4*)(x + (size_t)i * 8);
  f32x4 a = p[0], b = p[1];
  union { u16x8 v; unsigned u[4]; } o;
  o.u[0] = cvtpk(a[0], a[1]); o.u[1] = cvtpk(a[2], a[3]);
  o.u[2] = cvtpk(b[0], b[1]); o.u[3] = cvtpk(b[2], b[3]);
  *(u16x8*)(xb + (size_t)i * 8) = o.v;
}

// ---------------- prep: W [K][N] fp32 -> Wt [N][K] bf16 ----------------
// 64x64 tiles, float4 loads, LDS [64][65] f32, u16x8 stores. grid (16,16,4).
__global__ void transpose_w_kernel(const float* __restrict__ w0, const float* __restrict__ w1,
                                   const float* __restrict__ w2, const float* __restrict__ w3,
                                   u16* __restrict__ o0, u16* __restrict__ o1,
                                   u16* __restrict__ o2, u16* __restrict__ o3) {
  const float* W; u16* O;
  if      (blockIdx.z == 0) { W = w0; O = o0; }
  else if (blockIdx.z == 1) { W = w1; O = o1; }
  else if (blockIdx.z == 2) { W = w2; O = o2; }
  else                      { W = w3; O = o3; }
  __shared__ float t[64][65];
  int tid = threadIdx.x;
  int k0 = blockIdx.y * 64, n0 = blockIdx.x * 64;
  int lr = tid >> 4, lc = (tid & 15) * 4;
#pragma unroll
  for (int j = 0; j < 4; j++) {
    int row = j * 16 + lr;
    f32x4 v = *(const f32x4*)(W + (size_t)(k0 + row) * D_MODEL + n0 + lc);
    t[row][lc] = v[0]; t[row][lc + 1] = v[1]; t[row][lc + 2] = v[2]; t[row][lc + 3] = v[3];
  }
  __syncthreads();
  int nr = tid >> 2, ks = (tid & 3) * 16;
  union { u16x8 v; unsigned u[4]; } a, b;
#pragma unroll
  for (int i = 0; i < 4; i++) {
    a.u[i] = cvtpk(t[ks + 2 * i][nr],     t[ks + 2 * i + 1][nr]);
    b.u[i] = cvtpk(t[ks + 8 + 2 * i][nr], t[ks + 9 + 2 * i][nr]);
  }
  u16* op = O + (size_t)(n0 + nr) * D_MODEL + k0 + ks;
  *(u16x8*)op = a.v;
  *(u16x8*)(op + 8) = b.v;
}

// ---------------- GEMM: C = (A[M,K] * Bt[N,K]^T + bias) * oscale ----------------
// R18: 512 threads = 8 waves sharing the SAME 64 KB dbuf LDS (R13's move
// applied to GEMM): wave w (2x4 grid) owns 64x32 of the 128x128 tile
// (acc[4][2]), staging = 4 gload16/thread (2 A + 2 B chunks; chunk1 covers
// rows r0+64 — same swizzled cb since (r+64)&7 == r&7). Double-buffered
// K-loop, stage(k+1) at top, ONE barrier/iter. Both-sides XOR swizzle.
// trans==0: out[m*N + n]; trans==1 (bf16): out[n*M + perm64(m)]  (V^T for attn)
template<int BF16OUT>
__device__ __forceinline__ void gemm_body(const u16* __restrict__ A, const u16* __restrict__ Bt,
                                          const float* __restrict__ bias, void* __restrict__ outp,
                                          int M, int N, int K, float oscale, int trans,
                                          int m0, int n0) {
  __shared__ u16 As[2][128 * 64];   // 32 KB
  __shared__ u16 Bs[2][128 * 64];   // 32 KB
  int tid = threadIdx.x;
  int lane = tid & 63, w = tid >> 6;          // 8 waves
  int l15 = lane & 15, hi = lane >> 4;
  int wr = w >> 2, wc = w & 3;                // wave tile: rows wr*64, cols wc*32
  f32x4 acc[4][2] = {};

  // staging: thread covers chunk tid (rows 0..63) and chunk tid+512 (rows 64..127)
  int r0 = tid >> 3, cu = tid & 7;
  int cb = cu ^ (r0 & 7);
  const u16* ap0 = A  + (size_t)(m0 + r0)      * K + cb * 8;
  const u16* ap1 = A  + (size_t)(m0 + 64 + r0) * K + cb * 8;
  const u16* bp0 = Bt + (size_t)(n0 + r0)      * K + cb * 8;
  const u16* bp1 = Bt + (size_t)(n0 + 64 + r0) * K + cb * 8;

  // prologue: k-tile 0 -> buffer 0 (dest u16 offsets: chunk0 = w*512, chunk1 = 4096 + w*512)
  gload16(ap0, &As[0][w * 512]);
  gload16(ap1, &As[0][4096 + w * 512]);
  gload16(bp0, &Bs[0][w * 512]);
  gload16(bp1, &Bs[0][4096 + w * 512]);
  ap0 += 64; ap1 += 64; bp0 += 64; bp1 += 64;
  __syncthreads();

  const int NK = K / 64;
  for (int kk = 0; kk < NK; kk++) {
    int cur = kk & 1;
    if (kk + 1 < NK) {
      int nxt = cur ^ 1;
      gload16(ap0, &As[nxt][w * 512]);
      gload16(ap1, &As[nxt][4096 + w * 512]);
      gload16(bp0, &Bs[nxt][w * 512]);
      gload16(bp1, &Bs[nxt][4096 + w * 512]);
      ap0 += 64; ap1 += 64; bp0 += 64; bp1 += 64;
    }
#pragma unroll
    for (int s = 0; s < 2; s++) {
      bf16x8 af[4], bfr[2];
#pragma unroll
      for (int i = 0; i < 4; i++) {
        int ra = wr * 64 + i * 16 + l15;
        af[i] = *(const bf16x8*)&As[cur][ra * 64 + ((s * 4 + hi) ^ (ra & 7)) * 8];
      }
#pragma unroll
      for (int j = 0; j < 2; j++) {
        int rb = wc * 32 + j * 16 + l15;
        bfr[j] = *(const bf16x8*)&Bs[cur][rb * 64 + ((s * 4 + hi) ^ (rb & 7)) * 8];
      }
      __builtin_amdgcn_s_setprio(1);
#pragma unroll
      for (int i = 0; i < 4; i++)
#pragma unroll
        for (int j = 0; j < 2; j++)
          acc[i][j] = MFMA(af[i], bfr[j], acc[i][j]);
      __builtin_amdgcn_s_setprio(0);
    }
    __syncthreads();
  }

  // C/D layout: col = lane&15, row = (lane>>4)*4 + reg
  if (trans) {
#pragma unroll
    for (int j = 0; j < 2; j++) {
      int n = n0 + wc * 32 + j * 16 + l15;
      float bv = bias[n];
#pragma unroll
      for (int i = 0; i < 4; i++) {
        int mb = m0 + wr * 64 + i * 16 + hi * 4;
        int off = mb & 63;
        int colp = (off & 32) + (((off >> 2) & 3) << 3) + (((off >> 4) & 1) << 2);
        union { u16x4 v; unsigned u[2]; } t;
        t.u[0] = cvtpk((acc[i][j][0] + bv) * oscale, (acc[i][j][1] + bv) * oscale);
        t.u[1] = cvtpk((acc[i][j][2] + bv) * oscale, (acc[i][j][3] + bv) * oscale);
        *(u16x4*)((u16*)outp + (size_t)n * M + (mb - off) + colp) = t.v;
      }
    }
  } else {
#pragma unroll
    for (int j = 0; j < 2; j++) {
      int n = n0 + wc * 32 + j * 16 + l15;
      float bv = bias[n];
#pragma unroll
      for (int i = 0; i < 4; i++) {
        int mbase = m0 + wr * 64 + i * 16 + hi * 4;
#pragma unroll
        for (int r = 0; r < 4; r++) {
          float v = (acc[i][j][r] + bv) * oscale;
          if (BF16OUT) ((u16*)outp)[(size_t)(mbase + r) * N + n] = f2bf(v);
          else        ((float*)outp)[(size_t)(mbase + r) * N + n] = v;
        }
      }
    }
  }
}

// grid (8, 64, 3), 512 threads: flat f = (z*64+y)*8+x, nwg=1536, cpx=192
__global__ __launch_bounds__(512) void gemm_qkv_kernel(
    const u16* __restrict__ A,
    const u16* __restrict__ Btq, const u16* __restrict__ Btk, const u16* __restrict__ Btv,
    const float* __restrict__ bq, const float* __restrict__ bk, const float* __restrict__ bv,
    u16* __restrict__ oq, u16* __restrict__ ok, u16* __restrict__ ov) {
  int f = (blockIdx.z * 64 + blockIdx.y) * 8 + blockIdx.x;
  int wk = xcd_swz(f, 192);
  int bx = wk & 7, by = (wk >> 3) & 63, bz = wk >> 9;
  const u16* Bt; const float* bias; u16* o; float sc; int tr;
  if      (bz == 0) { Bt = Btq; bias = bq; o = oq; sc = K2LOG2E; tr = 0; }  // Q pre-scaled
  else if (bz == 1) { Bt = Btk; bias = bk; o = ok; sc = 1.0f; tr = 0; }
  else              { Bt = Btv; bias = bv; o = ov; sc = 1.0f; tr = 1; }     // V^T, perm'd
  gemm_body<1>(A, Bt, bias, o, MROWS, D_MODEL, D_MODEL, sc, tr, by * 128, bx * 128);
}

// grid (8, 64), 512 threads: flat f = y*8+x, nwg=512, cpx=64
__global__ __launch_bounds__(512) void gemm_f32out_kernel(
    const u16* __restrict__ A, const u16* __restrict__ Bt,
    const float* __restrict__ bias, float* __restrict__ out) {
  int f = blockIdx.y * 8 + blockIdx.x;
  int wk = xcd_swz(f, 64);
  int bx = wk & 7, by = wk >> 3;
  gemm_body<0>(A, Bt, bias, out, MROWS, D_MODEL, D_MODEL, 1.0f, 0, by * 128, bx * 128);
}

// ---------------- fused attention (R15/R17 — best measured: 78.9 µs) ----------------
// KVBLK=128: two 64-key subtiles per barrier period; double-buffered (64 KB).
// stage(g+1) issued at top, compute both subtiles of group g, ONE barrier.
// 8 waves QBLK=16, gload16 staging, both-sides XOR swizzle, V^T pre-permuted,
// fixed-shift softmax, ones-MFMA lsum, cvtpk packs, T1 XCD swizzle.
__global__ __launch_bounds__(512) void attn_kernel(
    const u16* __restrict__ Qb, const u16* __restrict__ Kb,
    const u16* __restrict__ Vt, u16* __restrict__ Ob) {
  __shared__ u16 Ks[2][2][64 * 64];   // [buf][sub], 32 KB total
  __shared__ u16 Vs[2][2][64 * 64];   // 32 KB total
  int tid = threadIdx.x;
  int lane = tid & 63, w = tid >> 6;            // w in [0,8)
  int l15 = lane & 15, hi = lane >> 4;
  int f = (blockIdx.z * NHEAD + blockIdx.y) * (T_SEQ / 128) + blockIdx.x;
  int wwg = xcd_swz(f, 128);              // grid 16*16*4 = 1024, cpx = 128
  int bx = wwg & 15, h = (wwg >> 4) & 15, b = wwg >> 8;
  int q0 = bx * 128 + w * 16;             // this wave's 16 q-rows
  size_t headoff = (size_t)b * T_SEQ * D_MODEL + h * DHEAD;
  const u16* vhead = Vt + (size_t)h * DHEAD * MROWS + (size_t)b * T_SEQ; // [d][t'], stride MROWS

  // Q fragments: row q0+l15, d = hf*32+hi*8
  const u16* qp = Qb + headoff + (size_t)(q0 + l15) * D_MODEL;
  bf16x8 qf0 = *(const bf16x8*)(qp + hi * 8);
  bf16x8 qf1 = *(const bf16x8*)(qp + 32 + hi * 8);

  f32x4 o[4] = {};           // o[dt]
  f32x4 lsum = {};           // ones-MFMA row-sum of P (rows equal)
  bf16x8 vones;
  { union { bf16x8 v; u16 e[8]; } c;
#pragma unroll
    for (int j = 0; j < 8; j++) c.e[j] = 0x3F80;  // bf16 1.0
    vones = c.v; }

  // staging: thread tid covers chunk tid of 512×16B per 64-key subtile;
  // row r = tid>>3, colblock cu = tid&7, source swizzled cb = cu ^ (r&7).
  int r0 = tid >> 3, cu = tid & 7;
  int cb = cu ^ (r0 & 7);
  const u16* ksrc = Kb + headoff + (size_t)r0 * D_MODEL + cb * 8;
  const u16* vsrc = vhead + (size_t)r0 * MROWS + cb * 8;   // V^T rows are d

  // prologue: key-group 0 (tiles 0,1) -> buffer 0
  gload16(ksrc,                &Ks[0][0][w * 512]);
  gload16(ksrc + 64 * D_MODEL, &Ks[0][1][w * 512]);
  gload16(vsrc,                &Vs[0][0][w * 512]);
  gload16(vsrc + 64,           &Vs[0][1][w * 512]);
  ksrc += 128 * D_MODEL; vsrc += 128;
  __syncthreads();

  const int NG = T_SEQ / 128;
  for (int g = 0; g < NG; g++) {
    int cur = g & 1;
    // issue next group's staging into the other buffer (read finished last iter)
    if (g + 1 < NG) {
      int nxt = cur ^ 1;
      gload16(ksrc,                &Ks[nxt][0][w * 512]);
      gload16(ksrc + 64 * D_MODEL, &Ks[nxt][1][w * 512]);
      gload16(vsrc,                &Vs[nxt][0][w * 512]);
      gload16(vsrc + 64,           &Vs[nxt][1][w * 512]);
      ksrc += 128 * D_MODEL; vsrc += 128;
    }

#pragma unroll
    for (int sub = 0; sub < 2; sub++) {
      // QK^T: S^T = K * Q^T (swizzled ds_read_b128 per key-quarter)
      f32x4 s[4];
      __builtin_amdgcn_s_setprio(1);
#pragma unroll
      for (int kq = 0; kq < 4; kq++) {
        int ra = kq * 16 + l15;
        bf16x8 kf0 = *(const bf16x8*)&Ks[cur][sub][ra * 64 + ((0 + hi) ^ (ra & 7)) * 8];
        bf16x8 kf1 = *(const bf16x8*)&Ks[cur][sub][ra * 64 + ((4 + hi) ^ (ra & 7)) * 8];
        f32x4 z = {};
        z = MFMA(kf0, qf0, z); z = MFMA(kf1, qf1, z);
        s[kq] = z;
      }
      __builtin_amdgcn_s_setprio(0);

      // V^T fragments (slot-ordered storage): swizzled ds_read_b128
      bf16x8 vf[4][2];
#pragma unroll
      for (int dt = 0; dt < 4; dt++) {
        int rv = dt * 16 + l15;
#pragma unroll
        for (int ks = 0; ks < 2; ks++)
          vf[dt][ks] = *(const bf16x8*)&Vs[cur][sub][rv * 64 + ((ks * 4 + hi) ^ (rv & 7)) * 8];
      }

      // fixed-shift softmax numerators: P = exp2(S')
#pragma unroll
      for (int kq = 0; kq < 4; kq++)
#pragma unroll
        for (int r = 0; r < 4; r++)
          s[kq][r] = __builtin_amdgcn_exp2f(s[kq][r]);

      // P -> bf16 B-operands; slot (hi,j) key = 32ks + 16(j>>2) + 4hi + (j&3)
      union PB { bf16x8 v; unsigned u[4]; };
      PB pb[2];
#pragma unroll
      for (int ks = 0; ks < 2; ks++) {
        pb[ks].u[0] = cvtpk(s[2*ks][0],   s[2*ks][1]);
        pb[ks].u[1] = cvtpk(s[2*ks][2],   s[2*ks][3]);
        pb[ks].u[2] = cvtpk(s[2*ks+1][0], s[2*ks+1][1]);
        pb[ks].u[3] = cvtpk(s[2*ks+1][2], s[2*ks+1][3]);
      }

      // O^T += V^T * P ; denominator lsum += ones^T * P
      __builtin_amdgcn_s_setprio(1);
#pragma unroll
      for (int ks = 0; ks < 2; ks++) {
#pragma unroll
        for (int dt = 0; dt < 4; dt++)
          o[dt] = MFMA(vf[dt][ks], pb[ks].v, o[dt]);
        lsum = MFMA(vones, pb[ks].v, lsum);
      }
      __builtin_amdgcn_s_setprio(0);
    }

    __syncthreads();   // drains vmcnt (staging) + lgkm; buffers consistent
  }

  // epilogue: l = lsum[0] (rows equal), scale, store
  float rs = 1.0f / lsum[0];
  u16* op = Ob + headoff + (size_t)(q0 + l15) * D_MODEL + hi * 4;
#pragma unroll
  for (int dt = 0; dt < 4; dt++) {
    union { u16x4 v; unsigned u[2]; } wo;
    wo.u[0] = cvtpk(o[dt][0] * rs, o[dt][1] * rs);
    wo.u[1] = cvtpk(o[dt][2] * rs, o[dt][3] * rs);
    *(u16x4*)(op + dt * 16) = wo.v;
  }
}

// ---------------- launch ----------------
extern "C" void kernel_launch(void* const* d_in, const int* in_sizes, int n_in,
                              void* d_out, int out_size, void* d_ws, size_t ws_size,
                              hipStream_t stream) {
  const float* x  = (const float*)d_in[0];
  const float* Wq = (const float*)d_in[1];
  const float* bq = (const float*)d_in[2];
  const float* Wk = (const float*)d_in[3];
  const float* bk = (const float*)d_in[4];
  const float* Wv = (const float*)d_in[5];
  const float* bv = (const float*)d_in[6];
  const float* Wo = (const float*)d_in[7];
  const float* bo = (const float*)d_in[8];

  char* ws = (char*)d_ws;
  u16* xb  = (u16*)(ws);
  u16* wqt = (u16*)(ws + ((size_t)16 << 20));
  u16* wkt = (u16*)(ws + ((size_t)18 << 20));
  u16* wvt = (u16*)(ws + ((size_t)20 << 20));
  u16* wot = (u16*)(ws + ((size_t)22 << 20));
  u16* qb  = (u16*)(ws + ((size_t)24 << 20));
  u16* kb  = (u16*)(ws + ((size_t)40 << 20));
  u16* vtb = (u16*)(ws + ((size_t)56 << 20));  // V^T [1024][8192], cols perm'd per 64
  u16* ab  = (u16*)(ws + ((size_t)72 << 20));

  cvt_x_kernel<<<(MROWS * D_MODEL / 8 + 255) / 256, 256, 0, stream>>>(x, xb, MROWS * D_MODEL / 8);
  transpose_w_kernel<<<dim3(16, 16, 4), 256, 0, stream>>>(Wq, Wk, Wv, Wo, wqt, wkt, wvt, wot);
  gemm_qkv_kernel<<<dim3(D_MODEL / 128, MROWS / 128, 3), 512, 0, stream>>>(
      xb, wqt, wkt, wvt, bq, bk, bv, qb, kb, vtb);
  attn_kernel<<<dim3(T_SEQ / 128, NHEAD, BATCH), 512, 0, stream>>>(qb, kb, vtb, ab);
  gemm_f32out_kernel<<<dim3(D_MODEL / 128, MROWS / 128), 512, 0, stream>>>(ab, wot, bo, (float*)d_out);
}

// Round 19
// 163.085 us; speedup vs baseline: 1.0723x; 1.0105x over previous
//
#include <hip/hip_runtime.h>
#include <hip/hip_bf16.h>

typedef unsigned short u16;
typedef u16  u16x8 __attribute__((ext_vector_type(8)));
typedef u16  u16x4 __attribute__((ext_vector_type(4)));
typedef short bf16x8 __attribute__((ext_vector_type(8)));
typedef float f32x4 __attribute__((ext_vector_type(4)));

#define D_MODEL 1024
#define T_SEQ   2048
#define BATCH   4
#define NHEAD   16
#define DHEAD   64
#define MROWS   (BATCH*T_SEQ)   /* 8192 */
#define K2LOG2E 0.18033688011112042f   /* log2(e)/sqrt(DHEAD) */

#define MFMA(a,b,c) __builtin_amdgcn_mfma_f32_16x16x32_bf16(a,b,c,0,0,0)

__device__ __forceinline__ u16 f2bf(float f) {
  __hip_bfloat16 h = __float2bfloat16(f);
  u16 r; __builtin_memcpy(&r, &h, 2); return r;
}
// v_cvt_pk_bf16_f32: low16 = bf16(lo), high16 = bf16(hi), RNE
__device__ __forceinline__ unsigned cvtpk(float lo, float hi) {
  unsigned r;
  asm("v_cvt_pk_bf16_f32 %0, %1, %2" : "=v"(r) : "v"(lo), "v"(hi));
  return r;
}

// async global -> LDS, 16B per lane (dest = wave-uniform base + lane*16)
__device__ __forceinline__ void gload16(const void* g, void* l) {
  __builtin_amdgcn_global_load_lds(
      (const __attribute__((address_space(1))) void*)g,
      (__attribute__((address_space(3))) void*)l, 16, 0, 0);
}

// T1 XCD swizzle (bijective when nwg % 8 == 0; cpx = nwg/8)
__device__ __forceinline__ int xcd_swz(int f, int cpx) {
  return (f & 7) * cpx + (f >> 3);
}

// ---------------- prep (merged): x fp32->bf16 AND W->W^T bf16 ----------------
// grid 5120 x 256: blocks [0,4096) convert x (8 f32 -> 8 bf16 per thread);
// blocks [4096,5120) transpose one 64x64 W tile (float4 loads, LDS [64][65],
// u16x8 packed stores). Merging saves one kernel-launch gap.
__global__ void prep_kernel(const float* __restrict__ x, u16* __restrict__ xb,
                            const float* __restrict__ w0, const float* __restrict__ w1,
                            const float* __restrict__ w2, const float* __restrict__ w3,
                            u16* __restrict__ o0, u16* __restrict__ o1,
                            u16* __restrict__ o2, u16* __restrict__ o3) {
  __shared__ float t[64][65];
  int bid = blockIdx.x, tid = threadIdx.x;
  if (bid < 4096) {
    int i = bid * 256 + tid;                       // n8 = 1048576 exactly
    const f32x4* p = (const f32x4*)(x + (size_t)i * 8);
    f32x4 a = p[0], b = p[1];
    union { u16x8 v; unsigned u[4]; } o;
    o.u[0] = cvtpk(a[0], a[1]); o.u[1] = cvtpk(a[2], a[3]);
    o.u[2] = cvtpk(b[0], b[1]); o.u[3] = cvtpk(b[2], b[3]);
    *(u16x8*)(xb + (size_t)i * 8) = o.v;
    return;
  }
  int idx = bid - 4096;
  int bx = idx & 15, by = (idx >> 4) & 15, bz = idx >> 8;
  const float* W; u16* O;
  if      (bz == 0) { W = w0; O = o0; }
  else if (bz == 1) { W = w1; O = o1; }
  else if (bz == 2) { W = w2; O = o2; }
  else              { W = w3; O = o3; }
  int k0 = by * 64, n0 = bx * 64;
  int lr = tid >> 4, lc = (tid & 15) * 4;
#pragma unroll
  for (int j = 0; j < 4; j++) {
    int row = j * 16 + lr;
    f32x4 v = *(const f32x4*)(W + (size_t)(k0 + row) * D_MODEL + n0 + lc);
    t[row][lc] = v[0]; t[row][lc + 1] = v[1]; t[row][lc + 2] = v[2]; t[row][lc + 3] = v[3];
  }
  __syncthreads();
  int nr = tid >> 2, ks = (tid & 3) * 16;
  union { u16x8 v; unsigned u[4]; } a, b;
#pragma unroll
  for (int i = 0; i < 4; i++) {
    a.u[i] = cvtpk(t[ks + 2 * i][nr],     t[ks + 2 * i + 1][nr]);
    b.u[i] = cvtpk(t[ks + 8 + 2 * i][nr], t[ks + 9 + 2 * i][nr]);
  }
  u16* op = O + (size_t)(n0 + nr) * D_MODEL + k0 + ks;
  *(u16x8*)op = a.v;
  *(u16x8*)(op + 8) = b.v;
}

// ---------------- GEMM: C = (A[M,K] * Bt[N,K]^T + bias) * oscale ----------------
// 512 threads = 8 waves sharing 64 KB dbuf LDS; wave w (2x4) owns 64x32 of the
// 128x128 tile (acc[4][2]); staging 4 gload16/thread; dbuf K-loop, stage(k+1)
// at top, ONE barrier/iter; both-sides XOR swizzle cb ^= (row&7).
// trans==0: out[m*N + n]; trans==1 (bf16): out[n*M + perm64(m)]  (V^T for attn)
template<int BF16OUT>
__device__ __forceinline__ void gemm_body(const u16* __restrict__ A, const u16* __restrict__ Bt,
                                          const float* __restrict__ bias, void* __restrict__ outp,
                                          int M, int N, int K, float oscale, int trans,
                                          int m0, int n0) {
  __shared__ u16 As[2][128 * 64];   // 32 KB
  __shared__ u16 Bs[2][128 * 64];   // 32 KB
  int tid = threadIdx.x;
  int lane = tid & 63, w = tid >> 6;          // 8 waves
  int l15 = lane & 15, hi = lane >> 4;
  int wr = w >> 2, wc = w & 3;                // wave tile: rows wr*64, cols wc*32
  f32x4 acc[4][2] = {};

  int r0 = tid >> 3, cu = tid & 7;
  int cb = cu ^ (r0 & 7);
  const u16* ap0 = A  + (size_t)(m0 + r0)      * K + cb * 8;
  const u16* ap1 = A  + (size_t)(m0 + 64 + r0) * K + cb * 8;
  const u16* bp0 = Bt + (size_t)(n0 + r0)      * K + cb * 8;
  const u16* bp1 = Bt + (size_t)(n0 + 64 + r0) * K + cb * 8;

  gload16(ap0, &As[0][w * 512]);
  gload16(ap1, &As[0][4096 + w * 512]);
  gload16(bp0, &Bs[0][w * 512]);
  gload16(bp1, &Bs[0][4096 + w * 512]);
  ap0 += 64; ap1 += 64; bp0 += 64; bp1 += 64;
  __syncthreads();

  const int NK = K / 64;
  for (int kk = 0; kk < NK; kk++) {
    int cur = kk & 1;
    if (kk + 1 < NK) {
      int nxt = cur ^ 1;
      gload16(ap0, &As[nxt][w * 512]);
      gload16(ap1, &As[nxt][4096 + w * 512]);
      gload16(bp0, &Bs[nxt][w * 512]);
      gload16(bp1, &Bs[nxt][4096 + w * 512]);
      ap0 += 64; ap1 += 64; bp0 += 64; bp1 += 64;
    }
#pragma unroll
    for (int s = 0; s < 2; s++) {
      bf16x8 af[4], bfr[2];
#pragma unroll
      for (int i = 0; i < 4; i++) {
        int ra = wr * 64 + i * 16 + l15;
        af[i] = *(const bf16x8*)&As[cur][ra * 64 + ((s * 4 + hi) ^ (ra & 7)) * 8];
      }
#pragma unroll
      for (int j = 0; j < 2; j++) {
        int rb = wc * 32 + j * 16 + l15;
        bfr[j] = *(const bf16x8*)&Bs[cur][rb * 64 + ((s * 4 + hi) ^ (rb & 7)) * 8];
      }
      __builtin_amdgcn_s_setprio(1);
#pragma unroll
      for (int i = 0; i < 4; i++)
#pragma unroll
        for (int j = 0; j < 2; j++)
          acc[i][j] = MFMA(af[i], bfr[j], acc[i][j]);
      __builtin_amdgcn_s_setprio(0);
    }
    __syncthreads();
  }

  // C/D layout: col = lane&15, row = (lane>>4)*4 + reg
  if (trans) {
#pragma unroll
    for (int j = 0; j < 2; j++) {
      int n = n0 + wc * 32 + j * 16 + l15;
      float bv = bias[n];
#pragma unroll
      for (int i = 0; i < 4; i++) {
        int mb = m0 + wr * 64 + i * 16 + hi * 4;
        int off = mb & 63;
        int colp = (off & 32) + (((off >> 2) & 3) << 3) + (((off >> 4) & 1) << 2);
        union { u16x4 v; unsigned u[2]; } t;
        t.u[0] = cvtpk((acc[i][j][0] + bv) * oscale, (acc[i][j][1] + bv) * oscale);
        t.u[1] = cvtpk((acc[i][j][2] + bv) * oscale, (acc[i][j][3] + bv) * oscale);
        *(u16x4*)((u16*)outp + (size_t)n * M + (mb - off) + colp) = t.v;
      }
    }
  } else {
#pragma unroll
    for (int j = 0; j < 2; j++) {
      int n = n0 + wc * 32 + j * 16 + l15;
      float bv = bias[n];
#pragma unroll
      for (int i = 0; i < 4; i++) {
        int mbase = m0 + wr * 64 + i * 16 + hi * 4;
#pragma unroll
        for (int r = 0; r < 4; r++) {
          float v = (acc[i][j][r] + bv) * oscale;
          if (BF16OUT) ((u16*)outp)[(size_t)(mbase + r) * N + n] = f2bf(v);
          else        ((float*)outp)[(size_t)(mbase + r) * N + n] = v;
        }
      }
    }
  }
}

// grid (8, 64, 3), 512 threads: flat f = (z*64+y)*8+x, nwg=1536, cpx=192
__global__ __launch_bounds__(512) void gemm_qkv_kernel(
    const u16* __restrict__ A,
    const u16* __restrict__ Btq, const u16* __restrict__ Btk, const u16* __restrict__ Btv,
    const float* __restrict__ bq, const float* __restrict__ bk, const float* __restrict__ bv,
    u16* __restrict__ oq, u16* __restrict__ ok, u16* __restrict__ ov) {
  int f = (blockIdx.z * 64 + blockIdx.y) * 8 + blockIdx.x;
  int wk = xcd_swz(f, 192);
  int bx = wk & 7, by = (wk >> 3) & 63, bz = wk >> 9;
  const u16* Bt; const float* bias; u16* o; float sc; int tr;
  if      (bz == 0) { Bt = Btq; bias = bq; o = oq; sc = K2LOG2E; tr = 0; }  // Q pre-scaled
  else if (bz == 1) { Bt = Btk; bias = bk; o = ok; sc = 1.0f; tr = 0; }
  else              { Bt = Btv; bias = bv; o = ov; sc = 1.0f; tr = 1; }     // V^T, perm'd
  gemm_body<1>(A, Bt, bias, o, MROWS, D_MODEL, D_MODEL, sc, tr, by * 128, bx * 128);
}

// grid (8, 64), 512 threads: flat f = y*8+x, nwg=512, cpx=64
__global__ __launch_bounds__(512) void gemm_f32out_kernel(
    const u16* __restrict__ A, const u16* __restrict__ Bt,
    const float* __restrict__ bias, float* __restrict__ out) {
  int f = blockIdx.y * 8 + blockIdx.x;
  int wk = xcd_swz(f, 64);
  int bx = wk & 7, by = wk >> 3;
  gemm_body<0>(A, Bt, bias, out, MROWS, D_MODEL, D_MODEL, 1.0f, 0, by * 128, bx * 128);
}

// ---------------- fused attention (best measured: 78.7-79.5 µs) ----------------
// KVBLK=128: two 64-key subtiles per barrier period; double-buffered (64 KB).
// stage(g+1) issued at top, compute both subtiles of group g, ONE barrier.
// 8 waves QBLK=16, gload16 staging, both-sides XOR swizzle, V^T pre-permuted,
// fixed-shift softmax, ones-MFMA lsum, cvtpk packs, T1 XCD swizzle.
__global__ __launch_bounds__(512) void attn_kernel(
    const u16* __restrict__ Qb, const u16* __restrict__ Kb,
    const u16* __restrict__ Vt, u16* __restrict__ Ob) {
  __shared__ u16 Ks[2][2][64 * 64];   // [buf][sub], 32 KB total
  __shared__ u16 Vs[2][2][64 * 64];   // 32 KB total
  int tid = threadIdx.x;
  int lane = tid & 63, w = tid >> 6;            // w in [0,8)
  int l15 = lane & 15, hi = lane >> 4;
  int f = (blockIdx.z * NHEAD + blockIdx.y) * (T_SEQ / 128) + blockIdx.x;
  int wwg = xcd_swz(f, 128);              // grid 16*16*4 = 1024, cpx = 128
  int bx = wwg & 15, h = (wwg >> 4) & 15, b = wwg >> 8;
  int q0 = bx * 128 + w * 16;             // this wave's 16 q-rows
  size_t headoff = (size_t)b * T_SEQ * D_MODEL + h * DHEAD;
  const u16* vhead = Vt + (size_t)h * DHEAD * MROWS + (size_t)b * T_SEQ; // [d][t'], stride MROWS

  // Q fragments: row q0+l15, d = hf*32+hi*8
  const u16* qp = Qb + headoff + (size_t)(q0 + l15) * D_MODEL;
  bf16x8 qf0 = *(const bf16x8*)(qp + hi * 8);
  bf16x8 qf1 = *(const bf16x8*)(qp + 32 + hi * 8);

  f32x4 o[4] = {};           // o[dt]
  f32x4 lsum = {};           // ones-MFMA row-sum of P (rows equal)
  bf16x8 vones;
  { union { bf16x8 v; u16 e[8]; } c;
#pragma unroll
    for (int j = 0; j < 8; j++) c.e[j] = 0x3F80;  // bf16 1.0
    vones = c.v; }

  // staging: thread tid covers chunk tid of 512×16B per 64-key subtile;
  // row r = tid>>3, colblock cu = tid&7, source swizzled cb = cu ^ (r&7).
  int r0 = tid >> 3, cu = tid & 7;
  int cb = cu ^ (r0 & 7);
  const u16* ksrc = Kb + headoff + (size_t)r0 * D_MODEL + cb * 8;
  const u16* vsrc = vhead + (size_t)r0 * MROWS + cb * 8;   // V^T rows are d

  // prologue: key-group 0 (tiles 0,1) -> buffer 0
  gload16(ksrc,                &Ks[0][0][w * 512]);
  gload16(ksrc + 64 * D_MODEL, &Ks[0][1][w * 512]);
  gload16(vsrc,                &Vs[0][0][w * 512]);
  gload16(vsrc + 64,           &Vs[0][1][w * 512]);
  ksrc += 128 * D_MODEL; vsrc += 128;
  __syncthreads();

  const int NG = T_SEQ / 128;
  for (int g = 0; g < NG; g++) {
    int cur = g & 1;
    // issue next group's staging into the other buffer (read finished last iter)
    if (g + 1 < NG) {
      int nxt = cur ^ 1;
      gload16(ksrc,                &Ks[nxt][0][w * 512]);
      gload16(ksrc + 64 * D_MODEL, &Ks[nxt][1][w * 512]);
      gload16(vsrc,                &Vs[nxt][0][w * 512]);
      gload16(vsrc + 64,           &Vs[nxt][1][w * 512]);
      ksrc += 128 * D_MODEL; vsrc += 128;
    }

#pragma unroll
    for (int sub = 0; sub < 2; sub++) {
      // QK^T: S^T = K * Q^T (swizzled ds_read_b128 per key-quarter)
      f32x4 s[4];
      __builtin_amdgcn_s_setprio(1);
#pragma unroll
      for (int kq = 0; kq < 4; kq++) {
        int ra = kq * 16 + l15;
        bf16x8 kf0 = *(const bf16x8*)&Ks[cur][sub][ra * 64 + ((0 + hi) ^ (ra & 7)) * 8];
        bf16x8 kf1 = *(const bf16x8*)&Ks[cur][sub][ra * 64 + ((4 + hi) ^ (ra & 7)) * 8];
        f32x4 z = {};
        z = MFMA(kf0, qf0, z); z = MFMA(kf1, qf1, z);
        s[kq] = z;
      }
      __builtin_amdgcn_s_setprio(0);

      // V^T fragments (slot-ordered storage): swizzled ds_read_b128
      bf16x8 vf[4][2];
#pragma unroll
      for (int dt = 0; dt < 4; dt++) {
        int rv = dt * 16 + l15;
#pragma unroll
        for (int ks = 0; ks < 2; ks++)
          vf[dt][ks] = *(const bf16x8*)&Vs[cur][sub][rv * 64 + ((ks * 4 + hi) ^ (rv & 7)) * 8];
      }

      // fixed-shift softmax numerators: P = exp2(S')
#pragma unroll
      for (int kq = 0; kq < 4; kq++)
#pragma unroll
        for (int r = 0; r < 4; r++)
          s[kq][r] = __builtin_amdgcn_exp2f(s[kq][r]);

      // P -> bf16 B-operands; slot (hi,j) key = 32ks + 16(j>>2) + 4hi + (j&3)
      union PB { bf16x8 v; unsigned u[4]; };
      PB pb[2];
#pragma unroll
      for (int ks = 0; ks < 2; ks++) {
        pb[ks].u[0] = cvtpk(s[2*ks][0],   s[2*ks][1]);
        pb[ks].u[1] = cvtpk(s[2*ks][2],   s[2*ks][3]);
        pb[ks].u[2] = cvtpk(s[2*ks+1][0], s[2*ks+1][1]);
        pb[ks].u[3] = cvtpk(s[2*ks+1][2], s[2*ks+1][3]);
      }

      // O^T += V^T * P ; denominator lsum += ones^T * P
      __builtin_amdgcn_s_setprio(1);
#pragma unroll
      for (int ks = 0; ks < 2; ks++) {
#pragma unroll
        for (int dt = 0; dt < 4; dt++)
          o[dt] = MFMA(vf[dt][ks], pb[ks].v, o[dt]);
        lsum = MFMA(vones, pb[ks].v, lsum);
      }
      __builtin_amdgcn_s_setprio(0);
    }

    __syncthreads();   // drains vmcnt (staging) + lgkm; buffers consistent
  }

  // epilogue: l = lsum[0] (rows equal), scale, store
  float rs = 1.0f / lsum[0];
  u16* op = Ob + headoff + (size_t)(q0 + l15) * D_MODEL + hi * 4;
#pragma unroll
  for (int dt = 0; dt < 4; dt++) {
    union { u16x4 v; unsigned u[2]; } wo;
    wo.u[0] = cvtpk(o[dt][0] * rs, o[dt][1] * rs);
    wo.u[1] = cvtpk(o[dt][2] * rs, o[dt][3] * rs);
    *(u16x4*)(op + dt * 16) = wo.v;
  }
}

// ---------------- launch ----------------
extern "C" void kernel_launch(void* const* d_in, const int* in_sizes, int n_in,
                              void* d_out, int out_size, void* d_ws, size_t ws_size,
                              hipStream_t stream) {
  const float* x  = (const float*)d_in[0];
  const float* Wq = (const float*)d_in[1];
  const float* bq = (const float*)d_in[2];
  const float* Wk = (const float*)d_in[3];
  const float* bk = (const float*)d_in[4];
  const float* Wv = (const float*)d_in[5];
  const float* bv = (const float*)d_in[6];
  const float* Wo = (const float*)d_in[7];
  const float* bo = (const float*)d_in[8];

  char* ws = (char*)d_ws;
  u16* xb  = (u16*)(ws);
  u16* wqt = (u16*)(ws + ((size_t)16 << 20));
  u16* wkt = (u16*)(ws + ((size_t)18 << 20));
  u16* wvt = (u16*)(ws + ((size_t)20 << 20));
  u16* wot = (u16*)(ws + ((size_t)22 << 20));
  u16* qb  = (u16*)(ws + ((size_t)24 << 20));
  u16* kb  = (u16*)(ws + ((size_t)40 << 20));
  u16* vtb = (u16*)(ws + ((size_t)56 << 20));  // V^T [1024][8192], cols perm'd per 64
  u16* ab  = (u16*)(ws + ((size_t)72 << 20));

  prep_kernel<<<5120, 256, 0, stream>>>(x, xb, Wq, Wk, Wv, Wo, wqt, wkt, wvt, wot);
  gemm_qkv_kernel<<<dim3(D_MODEL / 128, MROWS / 128, 3), 512, 0, stream>>>(
      xb, wqt, wkt, wvt, bq, bk, bv, qb, kb, vtb);
  attn_kernel<<<dim3(T_SEQ / 128, NHEAD, BATCH), 512, 0, stream>>>(qb, kb, vtb, ab);
  gemm_f32out_kernel<<<dim3(D_MODEL / 128, MROWS / 128), 512, 0, stream>>>(ab, wot, bo, (float*)d_out);
}